// Round 1
// baseline (591.146 us; speedup 1.0000x reference)
//
#include <hip/hip_runtime.h>

#define NTOK  8192
#define NHEAD 16
#define DDIM  128
#define HDIM  384
#define NEXP  8
#define TILE  64
#define MAXTILES 136   // sum_e ceil(cnt_e/64) <= 8192/64 + 7 = 135

typedef __attribute__((ext_vector_type(8))) short short8;   // 8 x bf16 (4 VGPRs)
typedef __attribute__((ext_vector_type(4))) float f32x4;    // MFMA accumulator

// ---------------- workspace layout (bytes) ----------------
#define SZ_W1P   (8UL*16*4*24*512*2)          // 12,582,912
#define OFF_W1P  0UL
#define OFF_WGP  (OFF_W1P + SZ_W1P)
#define OFF_W2P  (OFF_WGP + SZ_W1P)
#define SZ_W2P   (8UL*16*12*8*512*2)          // 12,582,912
#define OFF_ROUT (OFF_W2P + SZ_W2P)           // Routing[8192], 16B each
#define OFF_CNT  (OFF_ROUT + 8192UL*16)       // cnt[16], cur[16], tilecnt[2]
#define OFF_TAB  (OFF_CNT + 256)              // int4[2][136]
#define OFF_LIST (OFF_TAB + 2UL*MAXTILES*16)  // int[2][8192]
#define OFF_WL   (OFF_LIST + 2UL*8192*4)      // float[2][8192]

struct Routing { int i0, i1; float w0, w1; };

__device__ __forceinline__ unsigned short f2bf(float f) {
  unsigned int u = __float_as_uint(f);
  u += 0x7fffu + ((u >> 16) & 1u);            // round-to-nearest-even
  return (unsigned short)(u >> 16);
}

// ---------------- zero counters ----------------
__global__ void zero_kernel(int* __restrict__ p) {
  if (threadIdx.x < 16) p[threadIdx.x] = 0;
}

// ---------------- weight conversion: fp32 -> bf16 fragment-packed ----------------
// w1/w_gate: [e][n][d=128][h=384] -> frag [en][kk(4)][ct(24)][lane(64)][8]
// element (kk,ct,lane,j) = src[d = kk*32 + (lane>>4)*8 + j][h = ct*16 + (lane&15)]
__global__ __launch_bounds__(256) void convA_kernel(
    const float* __restrict__ w1, const float* __restrict__ wg,
    unsigned short* __restrict__ w1P, unsigned short* __restrict__ wgP) {
  __shared__ float ls[32][388];
  const int kk = blockIdx.x;          // 0..3
  const int en = blockIdx.y;          // 0..127
  const float* src = (blockIdx.z == 0 ? w1 : wg) + ((size_t)en * DDIM + kk * 32) * HDIM;
  unsigned short* dst = (blockIdx.z == 0 ? w1P : wgP) + ((size_t)en * 4 + kk) * (24 * 512);
  const int tid = threadIdx.x;
  #pragma unroll
  for (int i = 0; i < 12; ++i) {
    int f4 = i * 256 + tid;           // 3072 float4 = 32x384
    int row = f4 / 96, c4 = f4 % 96;
    float4 v = reinterpret_cast<const float4*>(src + (size_t)row * HDIM)[c4];
    ls[row][c4*4+0] = v.x; ls[row][c4*4+1] = v.y;
    ls[row][c4*4+2] = v.z; ls[row][c4*4+3] = v.w;
  }
  __syncthreads();
  #pragma unroll
  for (int i = 0; i < 6; ++i) {
    int fid = i * 256 + tid;          // 1536 = 24ct * 64lane
    int ct = fid >> 6, lane = fid & 63;
    int r0 = (lane >> 4) * 8, c = ct * 16 + (lane & 15);
    unsigned short o[8];
    #pragma unroll
    for (int j = 0; j < 8; ++j) o[j] = f2bf(ls[r0 + j][c]);
    reinterpret_cast<uint4*>(dst + (size_t)(ct * 64 + lane) * 8)[0] =
        make_uint4((unsigned)o[0] | ((unsigned)o[1] << 16),
                   (unsigned)o[2] | ((unsigned)o[3] << 16),
                   (unsigned)o[4] | ((unsigned)o[5] << 16),
                   (unsigned)o[6] | ((unsigned)o[7] << 16));
  }
}

// w2: [e][n][h=384][d=128] -> frag [en][kk(12)][ct(8)][lane(64)][8]
// element = src[h = kk*32 + (lane>>4)*8 + j][d = ct*16 + (lane&15)]
__global__ __launch_bounds__(256) void convB_kernel(
    const float* __restrict__ w2, unsigned short* __restrict__ w2P) {
  __shared__ float ls[32][132];
  const int kk = blockIdx.x;          // 0..11
  const int en = blockIdx.y;
  const float* src = w2 + ((size_t)en * HDIM + kk * 32) * DDIM;
  unsigned short* dst = w2P + ((size_t)en * 12 + kk) * (8 * 512);
  const int tid = threadIdx.x;
  #pragma unroll
  for (int i = 0; i < 4; ++i) {
    int f4 = i * 256 + tid;           // 1024 float4 = 32x128
    int row = f4 >> 5, c4 = f4 & 31;
    float4 v = reinterpret_cast<const float4*>(src + (size_t)row * DDIM)[c4];
    ls[row][c4*4+0] = v.x; ls[row][c4*4+1] = v.y;
    ls[row][c4*4+2] = v.z; ls[row][c4*4+3] = v.w;
  }
  __syncthreads();
  #pragma unroll
  for (int i = 0; i < 2; ++i) {
    int fid = i * 256 + tid;          // 512 = 8ct * 64lane
    int ct = fid >> 6, lane = fid & 63;
    int r0 = (lane >> 4) * 8, c = ct * 16 + (lane & 15);
    unsigned short o[8];
    #pragma unroll
    for (int j = 0; j < 8; ++j) o[j] = f2bf(ls[r0 + j][c]);
    reinterpret_cast<uint4*>(dst + (size_t)(ct * 64 + lane) * 8)[0] =
        make_uint4((unsigned)o[0] | ((unsigned)o[1] << 16),
                   (unsigned)o[2] | ((unsigned)o[3] << 16),
                   (unsigned)o[4] | ((unsigned)o[5] << 16),
                   (unsigned)o[6] | ((unsigned)o[7] << 16));
  }
}

// ---------------- router: logits, top-2, softmax, histogram ----------------
__global__ __launch_bounds__(256) void router_kernel(
    const float* __restrict__ x, const float* __restrict__ rw,
    Routing* __restrict__ routing, int* __restrict__ cnt) {
  extern __shared__ float rws[];      // 8 x 2048 f32 = 64KB
  const int tid = threadIdx.x;
  #pragma unroll
  for (int i = 0; i < 16; ++i) {
    int f4 = i * 256 + tid;
    reinterpret_cast<float4*>(rws)[f4] = reinterpret_cast<const float4*>(rw)[f4];
  }
  __syncthreads();
  const int wid = tid >> 6, lane = tid & 63;
  for (int tt = 0; tt < 4; ++tt) {
    int tok = blockIdx.x * 16 + wid * 4 + tt;
    const float4* xr = reinterpret_cast<const float4*>(x + (size_t)tok * 2048);
    float acc[8];
    #pragma unroll
    for (int e = 0; e < 8; ++e) acc[e] = 0.f;
    #pragma unroll
    for (int c = 0; c < 8; ++c) {
      float4 xv = xr[c * 64 + lane];
      #pragma unroll
      for (int e = 0; e < 8; ++e) {
        float4 wv = reinterpret_cast<const float4*>(rws)[e * 512 + c * 64 + lane];
        acc[e] += xv.x * wv.x + xv.y * wv.y + xv.z * wv.z + xv.w * wv.w;
      }
    }
    #pragma unroll
    for (int e = 0; e < 8; ++e) {
      acc[e] += __shfl_xor(acc[e], 32);
      acc[e] += __shfl_xor(acc[e], 16);
      acc[e] += __shfl_xor(acc[e], 8);
      acc[e] += __shfl_xor(acc[e], 4);
      acc[e] += __shfl_xor(acc[e], 2);
      acc[e] += __shfl_xor(acc[e], 1);
    }
    if (lane == 0) {
      int i0 = 0; float m0 = acc[0];
      #pragma unroll
      for (int e = 1; e < 8; ++e) if (acc[e] > m0) { m0 = acc[e]; i0 = e; }
      int i1 = -1; float m1 = -3.4e38f;
      #pragma unroll
      for (int e = 0; e < 8; ++e) if (e != i0 && acc[e] > m1) { m1 = acc[e]; i1 = e; }
      float ed = __expf(m1 - m0);                 // <= 1
      Routing r; r.i0 = i0; r.i1 = i1;
      r.w0 = 1.f / (1.f + ed); r.w1 = ed / (1.f + ed);
      routing[tok] = r;
      atomicAdd(&cnt[i0], 1);
      atomicAdd(&cnt[8 + i1], 1);
    }
  }
}

// ---------------- prefix sums + tile table ----------------
__global__ void prefix_kernel(const int* __restrict__ cnt, int* __restrict__ cur,
                              int4* __restrict__ table, int* __restrict__ tilecnt) {
  if (threadIdx.x != 0 || blockIdx.x != 0) return;
  for (int s = 0; s < 2; ++s) {
    int base = 0, idx = 0;
    for (int e = 0; e < 8; ++e) {
      int c = cnt[s * 8 + e];
      cur[s * 8 + e] = base;
      for (int t = 0; t < c; t += TILE) {
        int rc = c - t; if (rc > TILE) rc = TILE;
        table[s * MAXTILES + idx] = make_int4(e, base + t, rc, 0);
        idx++;
      }
      base += c;
    }
    tilecnt[s] = idx;
  }
}

// ---------------- scatter tokens into per-(slot,expert) lists ----------------
__global__ __launch_bounds__(256) void scatter_kernel(
    const Routing* __restrict__ routing, int* __restrict__ cur,
    int* __restrict__ list, float* __restrict__ wl) {
  int t = blockIdx.x * 256 + threadIdx.x;
  if (t >= NTOK) return;
  Routing r = routing[t];
  int p0 = atomicAdd(&cur[r.i0], 1);
  list[p0] = t; wl[p0] = r.w0;
  int p1 = atomicAdd(&cur[8 + r.i1], 1);
  list[NTOK + p1] = t; wl[NTOK + p1] = r.w1;
}

// ---------------- fused expert: (x@W1)*silu(x@Wg) @ W2, scaled ----------------
// block: 64-token tile x 1 head, 4 waves, 64KB dynamic LDS (xs 16KB + G 48KB)
__global__ __launch_bounds__(256) void expert_kernel(
    const float* __restrict__ x,
    const unsigned short* __restrict__ w1P,
    const unsigned short* __restrict__ wgP,
    const unsigned short* __restrict__ w2P,
    const int* __restrict__ list, const float* __restrict__ wl,
    const int4* __restrict__ table, const int* __restrict__ tilecnt,
    float* __restrict__ out, const int slot)
{
  extern __shared__ char smem[];
  char* xs = smem;            // 64 rows * 256B bf16, XOR-swizzled by (row&7)<<4
  char* G  = smem + 16384;    // 64 rows * 768B bf16, XOR-swizzled
  const int tile = blockIdx.x;
  if (tile >= tilecnt[slot]) return;
  const int4 tb = table[slot * MAXTILES + tile];
  const int e = tb.x, rbeg = tb.y, rcnt = tb.z;
  const int n = blockIdx.y;
  const int* lst = list + slot * NTOK + rbeg;
  const float* wls = wl + slot * NTOK + rbeg;
  const int tid = threadIdx.x;

  // ---- gather x rows: fp32 global -> bf16 swizzled LDS ----
  {
    const int cpos = tid & 31;      // float4 index within a 128-float row
    const int rsub = tid >> 5;      // 0..7
    #pragma unroll
    for (int it = 0; it < 8; ++it) {
      int row = it * 8 + rsub;
      unsigned int lo = 0, hi = 0;
      if (row < rcnt) {
        int tok = lst[row];
        float4 v = reinterpret_cast<const float4*>(x + ((size_t)tok * NHEAD + n) * DDIM)[cpos];
        lo = (unsigned)f2bf(v.x) | ((unsigned)f2bf(v.y) << 16);
        hi = (unsigned)f2bf(v.z) | ((unsigned)f2bf(v.w) << 16);
      }
      int byte = row * 256 + ((cpos * 8) ^ ((row & 7) << 4));
      *reinterpret_cast<uint2*>(xs + byte) = make_uint2(lo, hi);
    }
  }
  __syncthreads();

  const int wid = tid >> 6, lane = tid & 63;
  const int lr = lane & 15, lq = lane >> 4;
  const f32x4 z4 = {0.f, 0.f, 0.f, 0.f};

  // ---- stage 1: G = (x@W1) * silu(x@Wg) ----
  short8 a[4][4];   // A-frags: 4 row-tiles x 4 k-steps, held in regs
  #pragma unroll
  for (int mi = 0; mi < 4; ++mi)
    #pragma unroll
    for (int kk = 0; kk < 4; ++kk) {
      int row = mi * 16 + lr;
      int byte = row * 256 + (((kk * 32 + lq * 8) * 2) ^ ((row & 7) << 4));
      a[mi][kk] = *reinterpret_cast<const short8*>(xs + byte);
    }
  const unsigned short* w1b = w1P + (size_t)(e * NHEAD + n) * (4 * 24 * 512);
  const unsigned short* wgb = wgP + (size_t)(e * NHEAD + n) * (4 * 24 * 512);
  for (int ct = 0; ct < 6; ++ct) {
    const int ctg = wid * 6 + ct;   // col-tile 0..23 (H=384)
    f32x4 ah[4], ag[4];
    #pragma unroll
    for (int mi = 0; mi < 4; ++mi) { ah[mi] = z4; ag[mi] = z4; }
    #pragma unroll
    for (int kk = 0; kk < 4; ++kk) {
      short8 b1 = *reinterpret_cast<const short8*>(w1b + ((size_t)(kk * 24 + ctg) * 64 + lane) * 8);
      short8 bg = *reinterpret_cast<const short8*>(wgb + ((size_t)(kk * 24 + ctg) * 64 + lane) * 8);
      #pragma unroll
      for (int mi = 0; mi < 4; ++mi) {
        ah[mi] = __builtin_amdgcn_mfma_f32_16x16x32_bf16(a[mi][kk], b1, ah[mi], 0, 0, 0);
        ag[mi] = __builtin_amdgcn_mfma_f32_16x16x32_bf16(a[mi][kk], bg, ag[mi], 0, 0, 0);
      }
    }
    #pragma unroll
    for (int mi = 0; mi < 4; ++mi)
      #pragma unroll
      for (int r = 0; r < 4; ++r) {
        float h1 = ah[mi][r], g = ag[mi][r];
        float val = h1 * (g / (1.f + __expf(-g)));   // h1 * silu(g)
        int row = mi * 16 + lq * 4 + r;              // C-layout: row=(l>>4)*4+r
        int col = ctg * 16 + lr;                     //           col=l&15
        int byte = row * 768 + ((col * 2) ^ ((row & 7) << 4));
        *reinterpret_cast<unsigned short*>(G + byte) = f2bf(val);
      }
  }
  __syncthreads();

  // ---- stage 2: out_tile = G @ W2, scale by routing weight ----
  const int rg = wid >> 1, cg = wid & 1;  // 2x2 wave grid over (rows, cols)
  f32x4 acc[2][4];
  #pragma unroll
  for (int mi = 0; mi < 2; ++mi)
    #pragma unroll
    for (int ct = 0; ct < 4; ++ct) acc[mi][ct] = z4;
  const unsigned short* w2b = w2P + (size_t)(e * NHEAD + n) * (12 * 8 * 512);
  for (int kk = 0; kk < 12; ++kk) {
    int row0 = (rg * 2) * 16 + lr;
    int byte0 = row0 * 768 + (((kk * 32 + lq * 8) * 2) ^ ((row0 & 7) << 4));
    short8 a0 = *reinterpret_cast<const short8*>(G + byte0);
    int row1 = (rg * 2 + 1) * 16 + lr;
    int byte1 = row1 * 768 + (((kk * 32 + lq * 8) * 2) ^ ((row1 & 7) << 4));
    short8 a1 = *reinterpret_cast<const short8*>(G + byte1);
    #pragma unroll
    for (int ct = 0; ct < 4; ++ct) {
      short8 b = *reinterpret_cast<const short8*>(w2b + ((size_t)(kk * 8 + cg * 4 + ct) * 64 + lane) * 8);
      acc[0][ct] = __builtin_amdgcn_mfma_f32_16x16x32_bf16(a0, b, acc[0][ct], 0, 0, 0);
      acc[1][ct] = __builtin_amdgcn_mfma_f32_16x16x32_bf16(a1, b, acc[1][ct], 0, 0, 0);
    }
  }
  #pragma unroll
  for (int mi = 0; mi < 2; ++mi)
    #pragma unroll
    for (int r = 0; r < 4; ++r) {
      int row = (rg * 2 + mi) * 16 + lq * 4 + r;
      if (row < rcnt) {
        int tok = lst[row];
        float wt = wls[row];
        float* op = out + ((size_t)tok * NHEAD + n) * DDIM;
        #pragma unroll
        for (int ct = 0; ct < 4; ++ct) {
          int col = (cg * 4 + ct) * 16 + lr;
          float v = acc[mi][ct][r] * wt;
          if (slot == 0) op[col] = v;   // pass 0: every token exactly once -> full coverage
          else          op[col] += v;   // pass 1: unique writer, stream-ordered after pass 0
        }
      }
    }
}

extern "C" void kernel_launch(void* const* d_in, const int* in_sizes, int n_in,
                              void* d_out, int out_size, void* d_ws, size_t ws_size,
                              hipStream_t stream) {
  const float* x  = (const float*)d_in[0];
  const float* rw = (const float*)d_in[1];
  const float* w1 = (const float*)d_in[2];
  const float* wg = (const float*)d_in[3];
  const float* w2 = (const float*)d_in[4];
  float* out = (float*)d_out;
  char* ws = (char*)d_ws;

  unsigned short* w1P = (unsigned short*)(ws + OFF_W1P);
  unsigned short* wgP = (unsigned short*)(ws + OFF_WGP);
  unsigned short* w2P = (unsigned short*)(ws + OFF_W2P);
  Routing* routing = (Routing*)(ws + OFF_ROUT);
  int* cnt = (int*)(ws + OFF_CNT);
  int* cur = cnt + 16;
  int* tilecnt = cnt + 32;
  int4* table = (int4*)(ws + OFF_TAB);
  int* list = (int*)(ws + OFF_LIST);
  float* wl = (float*)(ws + OFF_WL);

  zero_kernel<<<1, 64, 0, stream>>>(cnt);
  convA_kernel<<<dim3(4, 128, 2), 256, 0, stream>>>(w1, wg, w1P, wgP);
  convB_kernel<<<dim3(12, 128, 1), 256, 0, stream>>>(w2, w2P);
  router_kernel<<<512, 256, 65536, stream>>>(x, rw, routing, cnt);
  prefix_kernel<<<1, 32, 0, stream>>>(cnt, cur, table, tilecnt);
  scatter_kernel<<<32, 256, 0, stream>>>(routing, cur, list, wl);
  expert_kernel<<<dim3(MAXTILES, NHEAD), 256, 65536, stream>>>(
      x, w1P, wgP, w2P, list, wl, table, tilecnt, out, 0);
  expert_kernel<<<dim3(MAXTILES, NHEAD), 256, 65536, stream>>>(
      x, w1P, wgP, w2P, list, wl, table, tilecnt, out, 1);
}

// Round 2
// 578.872 us; speedup vs baseline: 1.0212x; 1.0212x over previous
//
#include <hip/hip_runtime.h>

#define NTOK  8192
#define NHEAD 16
#define DDIM  128
#define HDIM  384
#define NEXP  8
#define TILE  64
#define ENTRIES 2176   // per-slot work entries: >= 8 + 8*ceil(272)-ish; proven bound 8*272

typedef __attribute__((ext_vector_type(8))) short short8;   // 8 x bf16 (4 VGPRs)
typedef __attribute__((ext_vector_type(4))) float f32x4;    // MFMA accumulator

// ---------------- workspace layout (bytes) ----------------
#define SZ_W1P   (8UL*16*4*24*512*2)          // 12,582,912
#define OFF_W1P  0UL
#define OFF_WGP  (OFF_W1P + SZ_W1P)
#define OFF_W2P  (OFF_WGP + SZ_W1P)
#define SZ_W2P   (8UL*16*12*8*512*2)          // 12,582,912
#define OFF_ROUT (OFF_W2P + SZ_W2P)           // Routing[8192], 16B each
#define OFF_CNT  (OFF_ROUT + 8192UL*16)       // cnt[16], cur[16]
#define OFF_TAB  (OFF_CNT + 256)              // int4[2][ENTRIES]
#define OFF_LIST (OFF_TAB + 2UL*ENTRIES*16)   // int[2][8192]
#define OFF_WL   (OFF_LIST + 2UL*8192*4)      // float[2][8192]

struct Routing { int i0, i1; float w0, w1; };

__device__ __forceinline__ unsigned short f2bf(float f) {
  unsigned int u = __float_as_uint(f);
  u += 0x7fffu + ((u >> 16) & 1u);            // round-to-nearest-even
  return (unsigned short)(u >> 16);
}

// ---------------- zero counters ----------------
__global__ void zero_kernel(int* __restrict__ p) {
  if (threadIdx.x < 16) p[threadIdx.x] = 0;
}

// ---------------- weight conversion: fp32 -> bf16 fragment-packed ----------------
// w1/w_gate: [e][n][d=128][h=384] -> frag [en][kk(4)][ct(24)][lane(64)][8]
// element (kk,ct,lane,j) = src[d = kk*32 + (lane>>4)*8 + j][h = ct*16 + (lane&15)]
__global__ __launch_bounds__(256) void convA_kernel(
    const float* __restrict__ w1, const float* __restrict__ wg,
    unsigned short* __restrict__ w1P, unsigned short* __restrict__ wgP) {
  __shared__ float ls[32][388];
  const int kk = blockIdx.x;          // 0..3
  const int en = blockIdx.y;          // 0..127
  const float* src = (blockIdx.z == 0 ? w1 : wg) + ((size_t)en * DDIM + kk * 32) * HDIM;
  unsigned short* dst = (blockIdx.z == 0 ? w1P : wgP) + ((size_t)en * 4 + kk) * (24 * 512);
  const int tid = threadIdx.x;
  #pragma unroll
  for (int i = 0; i < 12; ++i) {
    int f4 = i * 256 + tid;           // 3072 float4 = 32x384
    int row = f4 / 96, c4 = f4 % 96;
    float4 v = reinterpret_cast<const float4*>(src + (size_t)row * HDIM)[c4];
    ls[row][c4*4+0] = v.x; ls[row][c4*4+1] = v.y;
    ls[row][c4*4+2] = v.z; ls[row][c4*4+3] = v.w;
  }
  __syncthreads();
  #pragma unroll
  for (int i = 0; i < 6; ++i) {
    int fid = i * 256 + tid;          // 1536 = 24ct * 64lane
    int ct = fid >> 6, lane = fid & 63;
    int r0 = (lane >> 4) * 8, c = ct * 16 + (lane & 15);
    unsigned short o[8];
    #pragma unroll
    for (int j = 0; j < 8; ++j) o[j] = f2bf(ls[r0 + j][c]);
    reinterpret_cast<uint4*>(dst + (size_t)(ct * 64 + lane) * 8)[0] =
        make_uint4((unsigned)o[0] | ((unsigned)o[1] << 16),
                   (unsigned)o[2] | ((unsigned)o[3] << 16),
                   (unsigned)o[4] | ((unsigned)o[5] << 16),
                   (unsigned)o[6] | ((unsigned)o[7] << 16));
  }
}

// w2: [e][n][h=384][d=128] -> frag [en][kk(12)][ct(8)][lane(64)][8]
// element = src[h = kk*32 + (lane>>4)*8 + j][d = ct*16 + (lane&15)]
__global__ __launch_bounds__(256) void convB_kernel(
    const float* __restrict__ w2, unsigned short* __restrict__ w2P) {
  __shared__ float ls[32][132];
  const int kk = blockIdx.x;          // 0..11
  const int en = blockIdx.y;
  const float* src = w2 + ((size_t)en * HDIM + kk * 32) * DDIM;
  unsigned short* dst = w2P + ((size_t)en * 12 + kk) * (8 * 512);
  const int tid = threadIdx.x;
  #pragma unroll
  for (int i = 0; i < 4; ++i) {
    int f4 = i * 256 + tid;           // 1024 float4 = 32x128
    int row = f4 >> 5, c4 = f4 & 31;
    float4 v = reinterpret_cast<const float4*>(src + (size_t)row * DDIM)[c4];
    ls[row][c4*4+0] = v.x; ls[row][c4*4+1] = v.y;
    ls[row][c4*4+2] = v.z; ls[row][c4*4+3] = v.w;
  }
  __syncthreads();
  #pragma unroll
  for (int i = 0; i < 2; ++i) {
    int fid = i * 256 + tid;          // 512 = 8ct * 64lane
    int ct = fid >> 6, lane = fid & 63;
    int r0 = (lane >> 4) * 8, c = ct * 16 + (lane & 15);
    unsigned short o[8];
    #pragma unroll
    for (int j = 0; j < 8; ++j) o[j] = f2bf(ls[r0 + j][c]);
    reinterpret_cast<uint4*>(dst + (size_t)(ct * 64 + lane) * 8)[0] =
        make_uint4((unsigned)o[0] | ((unsigned)o[1] << 16),
                   (unsigned)o[2] | ((unsigned)o[3] << 16),
                   (unsigned)o[4] | ((unsigned)o[5] << 16),
                   (unsigned)o[6] | ((unsigned)o[7] << 16));
  }
}

// ---------------- router: no LDS, 1 wave = 4 tokens, rw via L1 ----------------
__global__ __launch_bounds__(256) void router_kernel(
    const float* __restrict__ x, const float* __restrict__ rw,
    Routing* __restrict__ routing, int* __restrict__ cnt) {
  const int lane = threadIdx.x & 63;
  const int wgid = blockIdx.x * 4 + (threadIdx.x >> 6);
  const int tok0 = wgid * 4;
  float acc[4][8];
  #pragma unroll
  for (int t = 0; t < 4; ++t)
    #pragma unroll
    for (int e = 0; e < 8; ++e) acc[t][e] = 0.f;
  const float4* xr = reinterpret_cast<const float4*>(x);
  const float4* wr = reinterpret_cast<const float4*>(rw);
  #pragma unroll
  for (int c = 0; c < 8; ++c) {
    float4 wv[8];
    #pragma unroll
    for (int e = 0; e < 8; ++e) wv[e] = wr[e * 512 + c * 64 + lane];
    #pragma unroll
    for (int t = 0; t < 4; ++t) {
      float4 xv = xr[(size_t)(tok0 + t) * 512 + c * 64 + lane];
      #pragma unroll
      for (int e = 0; e < 8; ++e)
        acc[t][e] += xv.x * wv[e].x + xv.y * wv[e].y + xv.z * wv[e].z + xv.w * wv[e].w;
    }
  }
  // xor 1,2,4: each 8-lane group holds its partial sum for all 8 experts
  #pragma unroll
  for (int t = 0; t < 4; ++t)
    #pragma unroll
    for (int e = 0; e < 8; ++e) {
      acc[t][e] += __shfl_xor(acc[t][e], 1);
      acc[t][e] += __shfl_xor(acc[t][e], 2);
      acc[t][e] += __shfl_xor(acc[t][e], 4);
    }
  const int l3 = lane & 7;
  #pragma unroll
  for (int t = 0; t < 4; ++t) {
    // lane selects expert (lane&7)'s partial, then sums across the 8 groups
    float v0 = (l3 & 1) ? acc[t][1] : acc[t][0];
    float v1 = (l3 & 1) ? acc[t][3] : acc[t][2];
    float v2 = (l3 & 1) ? acc[t][5] : acc[t][4];
    float v3 = (l3 & 1) ? acc[t][7] : acc[t][6];
    float u0 = (l3 & 2) ? v1 : v0;
    float u1 = (l3 & 2) ? v3 : v2;
    float sel = (l3 & 4) ? u1 : u0;
    sel += __shfl_xor(sel, 8);
    sel += __shfl_xor(sel, 16);
    sel += __shfl_xor(sel, 32);
    // lane e (e<8) now holds logit L_e; broadcast all 8 to every lane
    float le[8];
    #pragma unroll
    for (int e = 0; e < 8; ++e) le[e] = __shfl(sel, e);
    if (lane == 0) {
      int tok = tok0 + t;
      int i0 = 0; float m0 = le[0];
      #pragma unroll
      for (int e = 1; e < 8; ++e) if (le[e] > m0) { m0 = le[e]; i0 = e; }
      int i1 = -1; float m1 = -3.4e38f;
      #pragma unroll
      for (int e = 0; e < 8; ++e) if (e != i0 && le[e] > m1) { m1 = le[e]; i1 = e; }
      float ed = __expf(m1 - m0);                 // <= 1
      Routing r; r.i0 = i0; r.i1 = i1;
      r.w0 = 1.f / (1.f + ed); r.w1 = ed / (1.f + ed);
      routing[tok] = r;
      atomicAdd(&cnt[i0], 1);
      atomicAdd(&cnt[8 + i1], 1);
    }
  }
}

// ---------------- build: prefix offsets + XCD-grouped work table ----------------
// Work entry lid for slot s lives at table[s*ENTRIES + lid]; all tiles of a
// given (e,n) pair are placed at lid % 8 == n % 8 so they land on one XCD
// (linear block id round-robins XCDs) and share its L2 for the weight panel.
__global__ void build_kernel(const int* __restrict__ cnt, int* __restrict__ cur,
                             int4* __restrict__ table) {
  const int tid = threadIdx.x;
  for (int i = tid; i < 2 * ENTRIES; i += 256)
    table[i] = make_int4(0, 0, 0, 0);          // rcnt==0 sentinel -> early exit
  __syncthreads();
  if (tid < 16) {                               // cur[s*8+e] = per-slot prefix
    int s = tid >> 3, e = tid & 7;
    int base = 0;
    for (int k = 0; k < e; ++k) base += cnt[s * 8 + k];
    cur[tid] = base;
  }
  __syncthreads();
  if (tid < 16) {                               // one thread per (slot, xcd)
    int s = tid >> 3, xcd = tid & 7;
    int j = 0;
    int base = 0;
    for (int e = 0; e < 8; ++e) {
      int c = cnt[s * 8 + e];
      #pragma unroll
      for (int nn = 0; nn < 2; ++nn) {
        int n = xcd + nn * 8;                   // heads with n%8 == xcd
        for (int t = 0; t < c; t += TILE) {
          int rc = c - t; if (rc > TILE) rc = TILE;
          table[s * ENTRIES + xcd + 8 * j] = make_int4(e, base + t, rc, n);
          ++j;                                  // j <= 2*136 -> lid < ENTRIES
        }
      }
      base += c;
    }
  }
}

// ---------------- scatter tokens into per-(slot,expert) lists ----------------
__global__ __launch_bounds__(256) void scatter_kernel(
    const Routing* __restrict__ routing, int* __restrict__ cur,
    int* __restrict__ list, float* __restrict__ wl) {
  int t = blockIdx.x * 256 + threadIdx.x;
  if (t >= NTOK) return;
  Routing r = routing[t];
  int p0 = atomicAdd(&cur[r.i0], 1);
  list[p0] = t; wl[p0] = r.w0;
  int p1 = atomicAdd(&cur[8 + r.i1], 1);
  list[NTOK + p1] = t; wl[NTOK + p1] = r.w1;
}

// ---------------- fused expert: (x@W1)*silu(x@Wg) @ W2, scaled ----------------
// block: 64-token tile x 1 head, 4 waves, 64KB dynamic LDS (xs 16KB + G 48KB)
__global__ __launch_bounds__(256) void expert_kernel(
    const float* __restrict__ x,
    const unsigned short* __restrict__ w1P,
    const unsigned short* __restrict__ wgP,
    const unsigned short* __restrict__ w2P,
    const int* __restrict__ list, const float* __restrict__ wl,
    const int4* __restrict__ table,
    float* __restrict__ out, const int slot)
{
  extern __shared__ char smem[];
  char* xs = smem;            // 64 rows * 256B bf16, XOR-swizzled by (row&7)<<4
  char* G  = smem + 16384;    // 64 rows * 768B bf16, XOR-swizzled
  const int4 tb = table[slot * ENTRIES + blockIdx.x];
  const int e = tb.x, rbeg = tb.y, rcnt = tb.z, n = tb.w;
  if (rcnt == 0) return;
  const int* lst = list + slot * NTOK + rbeg;
  const float* wls = wl + slot * NTOK + rbeg;
  const int tid = threadIdx.x;

  // ---- gather x rows: fp32 global -> bf16 swizzled LDS ----
  {
    const int cpos = tid & 31;      // float4 index within a 128-float row
    const int rsub = tid >> 5;      // 0..7
    #pragma unroll
    for (int it = 0; it < 8; ++it) {
      int row = it * 8 + rsub;
      unsigned int lo = 0, hi = 0;
      if (row < rcnt) {
        int tok = lst[row];
        float4 v = reinterpret_cast<const float4*>(x + ((size_t)tok * NHEAD + n) * DDIM)[cpos];
        lo = (unsigned)f2bf(v.x) | ((unsigned)f2bf(v.y) << 16);
        hi = (unsigned)f2bf(v.z) | ((unsigned)f2bf(v.w) << 16);
      }
      int byte = row * 256 + ((cpos * 8) ^ ((row & 7) << 4));
      *reinterpret_cast<uint2*>(xs + byte) = make_uint2(lo, hi);
    }
  }
  __syncthreads();

  const int wid = tid >> 6, lane = tid & 63;
  const int lr = lane & 15, lq = lane >> 4;
  const f32x4 z4 = {0.f, 0.f, 0.f, 0.f};

  // ---- stage 1: G = (x@W1) * silu(x@Wg) ----
  short8 a[4][4];   // A-frags: 4 row-tiles x 4 k-steps, held in regs
  #pragma unroll
  for (int mi = 0; mi < 4; ++mi)
    #pragma unroll
    for (int kk = 0; kk < 4; ++kk) {
      int row = mi * 16 + lr;
      int byte = row * 256 + (((kk * 32 + lq * 8) * 2) ^ ((row & 7) << 4));
      a[mi][kk] = *reinterpret_cast<const short8*>(xs + byte);
    }
  const unsigned short* w1b = w1P + (size_t)(e * NHEAD + n) * (4 * 24 * 512);
  const unsigned short* wgb = wgP + (size_t)(e * NHEAD + n) * (4 * 24 * 512);
  for (int ct = 0; ct < 6; ++ct) {
    const int ctg = wid * 6 + ct;   // col-tile 0..23 (H=384)
    f32x4 ah[4], ag[4];
    #pragma unroll
    for (int mi = 0; mi < 4; ++mi) { ah[mi] = z4; ag[mi] = z4; }
    #pragma unroll
    for (int kk = 0; kk < 4; ++kk) {
      short8 b1 = *reinterpret_cast<const short8*>(w1b + ((size_t)(kk * 24 + ctg) * 64 + lane) * 8);
      short8 bg = *reinterpret_cast<const short8*>(wgb + ((size_t)(kk * 24 + ctg) * 64 + lane) * 8);
      #pragma unroll
      for (int mi = 0; mi < 4; ++mi) {
        ah[mi] = __builtin_amdgcn_mfma_f32_16x16x32_bf16(a[mi][kk], b1, ah[mi], 0, 0, 0);
        ag[mi] = __builtin_amdgcn_mfma_f32_16x16x32_bf16(a[mi][kk], bg, ag[mi], 0, 0, 0);
      }
    }
    #pragma unroll
    for (int mi = 0; mi < 4; ++mi)
      #pragma unroll
      for (int r = 0; r < 4; ++r) {
        float h1 = ah[mi][r], g = ag[mi][r];
        float val = h1 * (g / (1.f + __expf(-g)));   // h1 * silu(g)
        int row = mi * 16 + lq * 4 + r;              // C-layout: row=(l>>4)*4+r
        int col = ctg * 16 + lr;                     //           col=l&15
        int byte = row * 768 + ((col * 2) ^ ((row & 7) << 4));
        *reinterpret_cast<unsigned short*>(G + byte) = f2bf(val);
      }
  }
  __syncthreads();

  // ---- stage 2: out_tile = G @ W2, scale by routing weight ----
  const int rg = wid >> 1, cg = wid & 1;  // 2x2 wave grid over (rows, cols)
  f32x4 acc[2][4];
  #pragma unroll
  for (int mi = 0; mi < 2; ++mi)
    #pragma unroll
    for (int ct = 0; ct < 4; ++ct) acc[mi][ct] = z4;
  const unsigned short* w2b = w2P + (size_t)(e * NHEAD + n) * (12 * 8 * 512);
  for (int kk = 0; kk < 12; ++kk) {
    int row0 = (rg * 2) * 16 + lr;
    int byte0 = row0 * 768 + (((kk * 32 + lq * 8) * 2) ^ ((row0 & 7) << 4));
    short8 a0 = *reinterpret_cast<const short8*>(G + byte0);
    int row1 = (rg * 2 + 1) * 16 + lr;
    int byte1 = row1 * 768 + (((kk * 32 + lq * 8) * 2) ^ ((row1 & 7) << 4));
    short8 a1 = *reinterpret_cast<const short8*>(G + byte1);
    #pragma unroll
    for (int ct = 0; ct < 4; ++ct) {
      short8 b = *reinterpret_cast<const short8*>(w2b + ((size_t)(kk * 8 + cg * 4 + ct) * 64 + lane) * 8);
      acc[0][ct] = __builtin_amdgcn_mfma_f32_16x16x32_bf16(a0, b, acc[0][ct], 0, 0, 0);
      acc[1][ct] = __builtin_amdgcn_mfma_f32_16x16x32_bf16(a1, b, acc[1][ct], 0, 0, 0);
    }
  }
  #pragma unroll
  for (int mi = 0; mi < 2; ++mi)
    #pragma unroll
    for (int r = 0; r < 4; ++r) {
      int row = (rg * 2 + mi) * 16 + lq * 4 + r;
      if (row < rcnt) {
        int tok = lst[row];
        float wt = wls[row];
        float* op = out + ((size_t)tok * NHEAD + n) * DDIM;
        #pragma unroll
        for (int ct = 0; ct < 4; ++ct) {
          int col = (cg * 4 + ct) * 16 + lr;
          float v = acc[mi][ct][r] * wt;
          if (slot == 0) op[col] = v;   // pass 0: every token exactly once -> full coverage
          else          op[col] += v;   // pass 1: unique writer, stream-ordered after pass 0
        }
      }
    }
}

extern "C" void kernel_launch(void* const* d_in, const int* in_sizes, int n_in,
                              void* d_out, int out_size, void* d_ws, size_t ws_size,
                              hipStream_t stream) {
  const float* x  = (const float*)d_in[0];
  const float* rw = (const float*)d_in[1];
  const float* w1 = (const float*)d_in[2];
  const float* wg = (const float*)d_in[3];
  const float* w2 = (const float*)d_in[4];
  float* out = (float*)d_out;
  char* ws = (char*)d_ws;

  unsigned short* w1P = (unsigned short*)(ws + OFF_W1P);
  unsigned short* wgP = (unsigned short*)(ws + OFF_WGP);
  unsigned short* w2P = (unsigned short*)(ws + OFF_W2P);
  Routing* routing = (Routing*)(ws + OFF_ROUT);
  int* cnt = (int*)(ws + OFF_CNT);
  int* cur = cnt + 16;
  int4* table = (int4*)(ws + OFF_TAB);
  int* list = (int*)(ws + OFF_LIST);
  float* wl = (float*)(ws + OFF_WL);

  zero_kernel<<<1, 64, 0, stream>>>(cnt);
  convA_kernel<<<dim3(4, 128, 2), 256, 0, stream>>>(w1, wg, w1P, wgP);
  convB_kernel<<<dim3(12, 128, 1), 256, 0, stream>>>(w2, w2P);
  router_kernel<<<512, 256, 0, stream>>>(x, rw, routing, cnt);
  build_kernel<<<1, 256, 0, stream>>>(cnt, cur, table);
  scatter_kernel<<<32, 256, 0, stream>>>(routing, cur, list, wl);
  expert_kernel<<<ENTRIES, 256, 65536, stream>>>(
      x, w1P, wgP, w2P, list, wl, table, out, 0);
  expert_kernel<<<ENTRIES, 256, 65536, stream>>>(
      x, w1P, wgP, w2P, list, wl, table, out, 1);
}

// Round 3
// 358.348 us; speedup vs baseline: 1.6496x; 1.6154x over previous
//
#include <hip/hip_runtime.h>

#define NTOK  8192
#define NHEAD 16
#define DDIM  128
#define HDIM  384
#define NEXP  8
#define TILE  64
#define ENTRIES 2176   // per-slot work entries; worst case lid = 7 + 8*269 = 2159

typedef __attribute__((ext_vector_type(8))) short short8;   // 8 x bf16 (4 VGPRs)
typedef __attribute__((ext_vector_type(4))) float f32x4;    // MFMA accumulator

// ---------------- workspace layout (bytes) ----------------
#define SZ_W1P   (8UL*16*4*24*512*2)          // 12,582,912
#define OFF_W1P  0UL
#define OFF_WGP  (OFF_W1P + SZ_W1P)
#define OFF_W2P  (OFF_WGP + SZ_W1P)
#define SZ_W2P   (8UL*16*12*8*512*2)          // 12,582,912
#define OFF_ROUT (OFF_W2P + SZ_W2P)           // Routing[8192], 16B each
#define OFF_CNT  (OFF_ROUT + 8192UL*16)       // cnt[16], cur[16]
#define OFF_TAB  (OFF_CNT + 256)              // int4[2][ENTRIES]
#define OFF_LIST (OFF_TAB + 2UL*ENTRIES*16)   // int[2][8192]
#define OFF_WL   (OFF_LIST + 2UL*8192*4)      // float[2][8192]

struct Routing { int i0, i1; float w0, w1; };

__device__ __forceinline__ unsigned short f2bf(float f) {
  unsigned int u = __float_as_uint(f);
  u += 0x7fffu + ((u >> 16) & 1u);            // round-to-nearest-even
  return (unsigned short)(u >> 16);
}

// ---------------- weight conversion: fp32 -> bf16 fragment-packed ----------------
// w1/w_gate: [e][n][d=128][h=384] -> frag [en][kk(4)][ct(24)][lane(64)][8]
// element (kk,ct,lane,j) = src[d = kk*32 + (lane>>4)*8 + j][h = ct*16 + (lane&15)]
__global__ __launch_bounds__(256) void convA_kernel(
    const float* __restrict__ w1, const float* __restrict__ wg,
    unsigned short* __restrict__ w1P, unsigned short* __restrict__ wgP) {
  __shared__ float ls[32][388];
  const int kk = blockIdx.x;          // 0..3
  const int en = blockIdx.y;          // 0..127
  const float* src = (blockIdx.z == 0 ? w1 : wg) + ((size_t)en * DDIM + kk * 32) * HDIM;
  unsigned short* dst = (blockIdx.z == 0 ? w1P : wgP) + ((size_t)en * 4 + kk) * (24 * 512);
  const int tid = threadIdx.x;
  #pragma unroll
  for (int i = 0; i < 12; ++i) {
    int f4 = i * 256 + tid;           // 3072 float4 = 32x384
    int row = f4 / 96, c4 = f4 % 96;
    float4 v = reinterpret_cast<const float4*>(src + (size_t)row * HDIM)[c4];
    ls[row][c4*4+0] = v.x; ls[row][c4*4+1] = v.y;
    ls[row][c4*4+2] = v.z; ls[row][c4*4+3] = v.w;
  }
  __syncthreads();
  #pragma unroll
  for (int i = 0; i < 6; ++i) {
    int fid = i * 256 + tid;          // 1536 = 24ct * 64lane
    int ct = fid >> 6, lane = fid & 63;
    int r0 = (lane >> 4) * 8, c = ct * 16 + (lane & 15);
    unsigned short o[8];
    #pragma unroll
    for (int j = 0; j < 8; ++j) o[j] = f2bf(ls[r0 + j][c]);
    reinterpret_cast<uint4*>(dst + (size_t)(ct * 64 + lane) * 8)[0] =
        make_uint4((unsigned)o[0] | ((unsigned)o[1] << 16),
                   (unsigned)o[2] | ((unsigned)o[3] << 16),
                   (unsigned)o[4] | ((unsigned)o[5] << 16),
                   (unsigned)o[6] | ((unsigned)o[7] << 16));
  }
}

// w2: [e][n][h=384][d=128] -> frag [en][kk(12)][ct(8)][lane(64)][8]
// element = src[h = kk*32 + (lane>>4)*8 + j][d = ct*16 + (lane&15)]
__global__ __launch_bounds__(256) void convB_kernel(
    const float* __restrict__ w2, unsigned short* __restrict__ w2P) {
  __shared__ float ls[32][132];
  const int kk = blockIdx.x;          // 0..11
  const int en = blockIdx.y;
  const float* src = w2 + ((size_t)en * HDIM + kk * 32) * DDIM;
  unsigned short* dst = w2P + ((size_t)en * 12 + kk) * (8 * 512);
  const int tid = threadIdx.x;
  #pragma unroll
  for (int i = 0; i < 4; ++i) {
    int f4 = i * 256 + tid;           // 1024 float4 = 32x128
    int row = f4 >> 5, c4 = f4 & 31;
    float4 v = reinterpret_cast<const float4*>(src + (size_t)row * DDIM)[c4];
    ls[row][c4*4+0] = v.x; ls[row][c4*4+1] = v.y;
    ls[row][c4*4+2] = v.z; ls[row][c4*4+3] = v.w;
  }
  __syncthreads();
  #pragma unroll
  for (int i = 0; i < 2; ++i) {
    int fid = i * 256 + tid;          // 512 = 8ct * 64lane
    int ct = fid >> 6, lane = fid & 63;
    int r0 = (lane >> 4) * 8, c = ct * 16 + (lane & 15);
    unsigned short o[8];
    #pragma unroll
    for (int j = 0; j < 8; ++j) o[j] = f2bf(ls[r0 + j][c]);
    reinterpret_cast<uint4*>(dst + (size_t)(ct * 64 + lane) * 8)[0] =
        make_uint4((unsigned)o[0] | ((unsigned)o[1] << 16),
                   (unsigned)o[2] | ((unsigned)o[3] << 16),
                   (unsigned)o[4] | ((unsigned)o[5] << 16),
                   (unsigned)o[6] | ((unsigned)o[7] << 16));
  }
}

// ---------------- router: no LDS, no atomics, 1 wave = 4 tokens ----------------
__global__ __launch_bounds__(256) void router_kernel(
    const float* __restrict__ x, const float* __restrict__ rw,
    Routing* __restrict__ routing) {
  const int lane = threadIdx.x & 63;
  const int wgid = blockIdx.x * 4 + (threadIdx.x >> 6);
  const int tok0 = wgid * 4;
  float acc[4][8];
  #pragma unroll
  for (int t = 0; t < 4; ++t)
    #pragma unroll
    for (int e = 0; e < 8; ++e) acc[t][e] = 0.f;
  const float4* xr = reinterpret_cast<const float4*>(x);
  const float4* wr = reinterpret_cast<const float4*>(rw);
  #pragma unroll
  for (int c = 0; c < 8; ++c) {
    float4 wv[8];
    #pragma unroll
    for (int e = 0; e < 8; ++e) wv[e] = wr[e * 512 + c * 64 + lane];
    #pragma unroll
    for (int t = 0; t < 4; ++t) {
      float4 xv = xr[(size_t)(tok0 + t) * 512 + c * 64 + lane];
      #pragma unroll
      for (int e = 0; e < 8; ++e)
        acc[t][e] += xv.x * wv[e].x + xv.y * wv[e].y + xv.z * wv[e].z + xv.w * wv[e].w;
    }
  }
  // xor 1,2,4: each 8-lane group holds its partial sum for all 8 experts
  #pragma unroll
  for (int t = 0; t < 4; ++t)
    #pragma unroll
    for (int e = 0; e < 8; ++e) {
      acc[t][e] += __shfl_xor(acc[t][e], 1);
      acc[t][e] += __shfl_xor(acc[t][e], 2);
      acc[t][e] += __shfl_xor(acc[t][e], 4);
    }
  const int l3 = lane & 7;
  #pragma unroll
  for (int t = 0; t < 4; ++t) {
    // lane selects expert (lane&7)'s partial, then sums across the 8 groups
    float v0 = (l3 & 1) ? acc[t][1] : acc[t][0];
    float v1 = (l3 & 1) ? acc[t][3] : acc[t][2];
    float v2 = (l3 & 1) ? acc[t][5] : acc[t][4];
    float v3 = (l3 & 1) ? acc[t][7] : acc[t][6];
    float u0 = (l3 & 2) ? v1 : v0;
    float u1 = (l3 & 2) ? v3 : v2;
    float sel = (l3 & 4) ? u1 : u0;
    sel += __shfl_xor(sel, 8);
    sel += __shfl_xor(sel, 16);
    sel += __shfl_xor(sel, 32);
    // lane e (e<8) now holds logit L_e; broadcast all 8 to every lane
    float le[8];
    #pragma unroll
    for (int e = 0; e < 8; ++e) le[e] = __shfl(sel, e);
    if (lane == 0) {
      int tok = tok0 + t;
      int i0 = 0; float m0 = le[0];
      #pragma unroll
      for (int e = 1; e < 8; ++e) if (le[e] > m0) { m0 = le[e]; i0 = e; }
      int i1 = -1; float m1 = -3.4e38f;
      #pragma unroll
      for (int e = 0; e < 8; ++e) if (e != i0 && le[e] > m1) { m1 = le[e]; i1 = e; }
      float ed = __expf(m1 - m0);                 // <= 1
      Routing r; r.i0 = i0; r.i1 = i1;
      r.w0 = 1.f / (1.f + ed); r.w1 = ed / (1.f + ed);
      routing[tok] = r;
    }
  }
}

// ---------------- count: one block per (slot,expert), atomic-free ----------------
__global__ __launch_bounds__(256) void count_kernel(
    const Routing* __restrict__ routing, int* __restrict__ cnt) {
  const int s = blockIdx.x >> 3, e = blockIdx.x & 7;
  const int tid = threadIdx.x;
  int c = 0;
  for (int t = tid; t < NTOK; t += 256) {
    Routing r = routing[t];
    c += ((s == 0 ? r.i0 : r.i1) == e);
  }
  c += __shfl_xor(c, 32); c += __shfl_xor(c, 16); c += __shfl_xor(c, 8);
  c += __shfl_xor(c, 4);  c += __shfl_xor(c, 2);  c += __shfl_xor(c, 1);
  __shared__ int wsum[4];
  if ((tid & 63) == 0) wsum[tid >> 6] = c;
  __syncthreads();
  if (tid == 0) cnt[blockIdx.x] = wsum[0] + wsum[1] + wsum[2] + wsum[3];
}

// ---------------- build: prefix offsets + XCD-grouped work table ----------------
__global__ void build_kernel(const int* __restrict__ cnt, int* __restrict__ cur,
                             int4* __restrict__ table) {
  const int tid = threadIdx.x;
  for (int i = tid; i < 2 * ENTRIES; i += 256)
    table[i] = make_int4(0, 0, 0, 0);          // rcnt==0 sentinel -> early exit
  __syncthreads();
  if (tid < 16) {                               // cur[s*8+e] = per-slot prefix
    int s = tid >> 3, e = tid & 7;
    int base = 0;
    for (int k = 0; k < e; ++k) base += cnt[s * 8 + k];
    cur[tid] = base;
  }
  __syncthreads();
  if (tid < 16) {                               // one thread per (slot, xcd)
    int s = tid >> 3, xcd = tid & 7;
    int j = 0;
    int base = 0;
    for (int e = 0; e < 8; ++e) {
      int c = cnt[s * 8 + e];
      #pragma unroll
      for (int nn = 0; nn < 2; ++nn) {
        int n = xcd + nn * 8;                   // heads with n%8 == xcd
        for (int t = 0; t < c; t += TILE) {
          int rc = c - t; if (rc > TILE) rc = TILE;
          table[s * ENTRIES + xcd + 8 * j] = make_int4(e, base + t, rc, n);
          ++j;
        }
      }
      base += c;
    }
  }
}

// ---------------- compact: ordered, atomic-free scatter via block scan ----------------
__global__ __launch_bounds__(256) void compact_kernel(
    const Routing* __restrict__ routing, const int* __restrict__ cur,
    int* __restrict__ list, float* __restrict__ wl) {
  const int s = blockIdx.x >> 3, e = blockIdx.x & 7;
  const int tid = threadIdx.x;
  __shared__ int ps[256];
  int myc = 0;
  for (int t = tid; t < NTOK; t += 256) {
    Routing r = routing[t];
    myc += ((s == 0 ? r.i0 : r.i1) == e);
  }
  ps[tid] = myc;
  __syncthreads();
  for (int off = 1; off < 256; off <<= 1) {     // inclusive log-step scan
    int v = (tid >= off) ? ps[tid - off] : 0;
    __syncthreads();
    ps[tid] += v;
    __syncthreads();
  }
  int base = cur[blockIdx.x] + ps[tid] - myc;   // exclusive prefix + slot base
  for (int t = tid; t < NTOK; t += 256) {
    Routing r = routing[t];
    int ei = (s == 0 ? r.i0 : r.i1);
    if (ei == e) {
      list[s * NTOK + base] = t;
      wl[s * NTOK + base] = (s == 0 ? r.w0 : r.w1);
      ++base;
    }
  }
}

// ---------------- fused expert: (x@W1)*silu(x@Wg) @ W2, scaled ----------------
// block: 64-token tile x 1 head, 4 waves, 64KB dynamic LDS (xs 16KB + G 48KB)
__global__ __launch_bounds__(256) void expert_kernel(
    const float* __restrict__ x,
    const unsigned short* __restrict__ w1P,
    const unsigned short* __restrict__ wgP,
    const unsigned short* __restrict__ w2P,
    const int* __restrict__ list, const float* __restrict__ wl,
    const int4* __restrict__ table,
    float* __restrict__ out, const int slot)
{
  extern __shared__ char smem[];
  char* xs = smem;            // 64 rows * 256B bf16, XOR-swizzled by (row&7)<<4
  char* G  = smem + 16384;    // 64 rows * 768B bf16, XOR-swizzled
  const int4 tb = table[slot * ENTRIES + blockIdx.x];
  const int e = tb.x, rbeg = tb.y, rcnt = tb.z, n = tb.w;
  if (rcnt == 0) return;
  const int* lst = list + slot * NTOK + rbeg;
  const float* wls = wl + slot * NTOK + rbeg;
  const int tid = threadIdx.x;

  // ---- gather x rows: fp32 global -> bf16 swizzled LDS ----
  {
    const int cpos = tid & 31;      // float4 index within a 128-float row
    const int rsub = tid >> 5;      // 0..7
    #pragma unroll
    for (int it = 0; it < 8; ++it) {
      int row = it * 8 + rsub;
      unsigned int lo = 0, hi = 0;
      if (row < rcnt) {
        int tok = lst[row];
        float4 v = reinterpret_cast<const float4*>(x + ((size_t)tok * NHEAD + n) * DDIM)[cpos];
        lo = (unsigned)f2bf(v.x) | ((unsigned)f2bf(v.y) << 16);
        hi = (unsigned)f2bf(v.z) | ((unsigned)f2bf(v.w) << 16);
      }
      int byte = row * 256 + ((cpos * 8) ^ ((row & 7) << 4));
      *reinterpret_cast<uint2*>(xs + byte) = make_uint2(lo, hi);
    }
  }
  __syncthreads();

  const int wid = tid >> 6, lane = tid & 63;
  const int lr = lane & 15, lq = lane >> 4;
  const f32x4 z4 = {0.f, 0.f, 0.f, 0.f};

  // ---- stage 1: G = (x@W1) * silu(x@Wg) ----
  short8 a[4][4];   // A-frags: 4 row-tiles x 4 k-steps, held in regs
  #pragma unroll
  for (int mi = 0; mi < 4; ++mi)
    #pragma unroll
    for (int kk = 0; kk < 4; ++kk) {
      int row = mi * 16 + lr;
      int byte = row * 256 + (((kk * 32 + lq * 8) * 2) ^ ((row & 7) << 4));
      a[mi][kk] = *reinterpret_cast<const short8*>(xs + byte);
    }
  const unsigned short* w1b = w1P + (size_t)(e * NHEAD + n) * (4 * 24 * 512);
  const unsigned short* wgb = wgP + (size_t)(e * NHEAD + n) * (4 * 24 * 512);
  for (int ct = 0; ct < 6; ++ct) {
    const int ctg = wid * 6 + ct;   // col-tile 0..23 (H=384)
    f32x4 ah[4], ag[4];
    #pragma unroll
    for (int mi = 0; mi < 4; ++mi) { ah[mi] = z4; ag[mi] = z4; }
    #pragma unroll
    for (int kk = 0; kk < 4; ++kk) {
      short8 b1 = *reinterpret_cast<const short8*>(w1b + ((size_t)(kk * 24 + ctg) * 64 + lane) * 8);
      short8 bg = *reinterpret_cast<const short8*>(wgb + ((size_t)(kk * 24 + ctg) * 64 + lane) * 8);
      #pragma unroll
      for (int mi = 0; mi < 4; ++mi) {
        ah[mi] = __builtin_amdgcn_mfma_f32_16x16x32_bf16(a[mi][kk], b1, ah[mi], 0, 0, 0);
        ag[mi] = __builtin_amdgcn_mfma_f32_16x16x32_bf16(a[mi][kk], bg, ag[mi], 0, 0, 0);
      }
    }
    #pragma unroll
    for (int mi = 0; mi < 4; ++mi)
      #pragma unroll
      for (int r = 0; r < 4; ++r) {
        float h1 = ah[mi][r], g = ag[mi][r];
        float val = h1 * (g / (1.f + __expf(-g)));   // h1 * silu(g)
        int row = mi * 16 + lq * 4 + r;              // C-layout: row=(l>>4)*4+r
        int col = ctg * 16 + lr;                     //           col=l&15
        int byte = row * 768 + ((col * 2) ^ ((row & 7) << 4));
        *reinterpret_cast<unsigned short*>(G + byte) = f2bf(val);
      }
  }
  __syncthreads();

  // ---- stage 2: out_tile = G @ W2, scale by routing weight ----
  const int rg = wid >> 1, cg = wid & 1;  // 2x2 wave grid over (rows, cols)
  f32x4 acc[2][4];
  #pragma unroll
  for (int mi = 0; mi < 2; ++mi)
    #pragma unroll
    for (int ct = 0; ct < 4; ++ct) acc[mi][ct] = z4;
  const unsigned short* w2b = w2P + (size_t)(e * NHEAD + n) * (12 * 8 * 512);
  for (int kk = 0; kk < 12; ++kk) {
    int row0 = (rg * 2) * 16 + lr;
    int byte0 = row0 * 768 + (((kk * 32 + lq * 8) * 2) ^ ((row0 & 7) << 4));
    short8 a0 = *reinterpret_cast<const short8*>(G + byte0);
    int row1 = (rg * 2 + 1) * 16 + lr;
    int byte1 = row1 * 768 + (((kk * 32 + lq * 8) * 2) ^ ((row1 & 7) << 4));
    short8 a1 = *reinterpret_cast<const short8*>(G + byte1);
    #pragma unroll
    for (int ct = 0; ct < 4; ++ct) {
      short8 b = *reinterpret_cast<const short8*>(w2b + ((size_t)(kk * 8 + cg * 4 + ct) * 64 + lane) * 8);
      acc[0][ct] = __builtin_amdgcn_mfma_f32_16x16x32_bf16(a0, b, acc[0][ct], 0, 0, 0);
      acc[1][ct] = __builtin_amdgcn_mfma_f32_16x16x32_bf16(a1, b, acc[1][ct], 0, 0, 0);
    }
  }
  #pragma unroll
  for (int mi = 0; mi < 2; ++mi)
    #pragma unroll
    for (int r = 0; r < 4; ++r) {
      int row = (rg * 2 + mi) * 16 + lq * 4 + r;
      if (row < rcnt) {
        int tok = lst[row];
        float wt = wls[row];
        float* op = out + ((size_t)tok * NHEAD + n) * DDIM;
        #pragma unroll
        for (int ct = 0; ct < 4; ++ct) {
          int col = (cg * 4 + ct) * 16 + lr;
          float v = acc[mi][ct][r] * wt;
          if (slot == 0) op[col] = v;   // pass 0: every token exactly once -> full coverage
          else          op[col] += v;   // pass 1: unique writer, stream-ordered after pass 0
        }
      }
    }
}

extern "C" void kernel_launch(void* const* d_in, const int* in_sizes, int n_in,
                              void* d_out, int out_size, void* d_ws, size_t ws_size,
                              hipStream_t stream) {
  const float* x  = (const float*)d_in[0];
  const float* rw = (const float*)d_in[1];
  const float* w1 = (const float*)d_in[2];
  const float* wg = (const float*)d_in[3];
  const float* w2 = (const float*)d_in[4];
  float* out = (float*)d_out;
  char* ws = (char*)d_ws;

  unsigned short* w1P = (unsigned short*)(ws + OFF_W1P);
  unsigned short* wgP = (unsigned short*)(ws + OFF_WGP);
  unsigned short* w2P = (unsigned short*)(ws + OFF_W2P);
  Routing* routing = (Routing*)(ws + OFF_ROUT);
  int* cnt = (int*)(ws + OFF_CNT);
  int* cur = cnt + 16;
  int4* table = (int4*)(ws + OFF_TAB);
  int* list = (int*)(ws + OFF_LIST);
  float* wl = (float*)(ws + OFF_WL);

  convA_kernel<<<dim3(4, 128, 2), 256, 0, stream>>>(w1, wg, w1P, wgP);
  convB_kernel<<<dim3(12, 128, 1), 256, 0, stream>>>(w2, w2P);
  router_kernel<<<512, 256, 0, stream>>>(x, rw, routing);
  count_kernel<<<16, 256, 0, stream>>>(routing, cnt);
  build_kernel<<<1, 256, 0, stream>>>(cnt, cur, table);
  compact_kernel<<<16, 256, 0, stream>>>(routing, cur, list, wl);
  expert_kernel<<<ENTRIES, 256, 65536, stream>>>(
      x, w1P, wgP, w2P, list, wl, table, out, 0);
  expert_kernel<<<ENTRIES, 256, 65536, stream>>>(
      x, w1P, wgP, w2P, list, wl, table, out, 1);
}

// Round 4
// 337.926 us; speedup vs baseline: 1.7493x; 1.0604x over previous
//
#include <hip/hip_runtime.h>

#define NTOK  8192
#define NHEAD 16
#define DDIM  128
#define HDIM  384
#define NEXP  8
#define TILE  32
#define ENTRIES 4352   // per-slot work entries; worst case lid = 7 + 8*527 = 4223

typedef __attribute__((ext_vector_type(8))) short short8;   // 8 x bf16 (4 VGPRs)
typedef __attribute__((ext_vector_type(4))) float f32x4;    // MFMA accumulator

// ---------------- workspace layout (bytes) ----------------
#define SZ_W1P   (8UL*16*4*24*512*2)          // 12,582,912
#define OFF_W1P  0UL
#define OFF_WGP  (OFF_W1P + SZ_W1P)
#define OFF_W2P  (OFF_WGP + SZ_W1P)
#define SZ_W2P   (8UL*16*12*8*512*2)          // 12,582,912
#define OFF_ROUT (OFF_W2P + SZ_W2P)           // Routing[8192], 16B each
#define OFF_CNT  (OFF_ROUT + 8192UL*16)       // cnt[16], cur[16]
#define OFF_TAB  (OFF_CNT + 256)              // int4[2][ENTRIES]
#define OFF_LIST (OFF_TAB + 2UL*ENTRIES*16)   // int[2][8192]
#define OFF_WL   (OFF_LIST + 2UL*8192*4)      // float[2][8192]

struct Routing { int i0, i1; float w0, w1; };

__device__ __forceinline__ unsigned short f2bf(float f) {
  unsigned int u = __float_as_uint(f);
  u += 0x7fffu + ((u >> 16) & 1u);            // round-to-nearest-even
  return (unsigned short)(u >> 16);
}

// ---------------- weight conversion: fp32 -> bf16 fragment-packed ----------------
// w1/w_gate: [e][n][d=128][h=384] -> frag [en][kk(4)][ct(24)][lane(64)][8]
// element (kk,ct,lane,j) = src[d = kk*32 + (lane>>4)*8 + j][h = ct*16 + (lane&15)]
__global__ __launch_bounds__(256) void convA_kernel(
    const float* __restrict__ w1, const float* __restrict__ wg,
    unsigned short* __restrict__ w1P, unsigned short* __restrict__ wgP) {
  __shared__ float ls[32][388];
  const int kk = blockIdx.x;          // 0..3
  const int en = blockIdx.y;          // 0..127
  const float* src = (blockIdx.z == 0 ? w1 : wg) + ((size_t)en * DDIM + kk * 32) * HDIM;
  unsigned short* dst = (blockIdx.z == 0 ? w1P : wgP) + ((size_t)en * 4 + kk) * (24 * 512);
  const int tid = threadIdx.x;
  #pragma unroll
  for (int i = 0; i < 12; ++i) {
    int f4 = i * 256 + tid;           // 3072 float4 = 32x384
    int row = f4 / 96, c4 = f4 % 96;
    float4 v = reinterpret_cast<const float4*>(src + (size_t)row * HDIM)[c4];
    ls[row][c4*4+0] = v.x; ls[row][c4*4+1] = v.y;
    ls[row][c4*4+2] = v.z; ls[row][c4*4+3] = v.w;
  }
  __syncthreads();
  #pragma unroll
  for (int i = 0; i < 6; ++i) {
    int fid = i * 256 + tid;          // 1536 = 24ct * 64lane
    int ct = fid >> 6, lane = fid & 63;
    int r0 = (lane >> 4) * 8, c = ct * 16 + (lane & 15);
    unsigned short o[8];
    #pragma unroll
    for (int j = 0; j < 8; ++j) o[j] = f2bf(ls[r0 + j][c]);
    reinterpret_cast<uint4*>(dst + (size_t)(ct * 64 + lane) * 8)[0] =
        make_uint4((unsigned)o[0] | ((unsigned)o[1] << 16),
                   (unsigned)o[2] | ((unsigned)o[3] << 16),
                   (unsigned)o[4] | ((unsigned)o[5] << 16),
                   (unsigned)o[6] | ((unsigned)o[7] << 16));
  }
}

// w2: [e][n][h=384][d=128] -> frag [en][kk(12)][ct(8)][lane(64)][8]
// element = src[h = kk*32 + (lane>>4)*8 + j][d = ct*16 + (lane&15)]
__global__ __launch_bounds__(256) void convB_kernel(
    const float* __restrict__ w2, unsigned short* __restrict__ w2P) {
  __shared__ float ls[32][132];
  const int kk = blockIdx.x;          // 0..11
  const int en = blockIdx.y;
  const float* src = w2 + ((size_t)en * HDIM + kk * 32) * DDIM;
  unsigned short* dst = w2P + ((size_t)en * 12 + kk) * (8 * 512);
  const int tid = threadIdx.x;
  #pragma unroll
  for (int i = 0; i < 4; ++i) {
    int f4 = i * 256 + tid;           // 1024 float4 = 32x128
    int row = f4 >> 5, c4 = f4 & 31;
    float4 v = reinterpret_cast<const float4*>(src + (size_t)row * DDIM)[c4];
    ls[row][c4*4+0] = v.x; ls[row][c4*4+1] = v.y;
    ls[row][c4*4+2] = v.z; ls[row][c4*4+3] = v.w;
  }
  __syncthreads();
  #pragma unroll
  for (int i = 0; i < 2; ++i) {
    int fid = i * 256 + tid;          // 512 = 8ct * 64lane
    int ct = fid >> 6, lane = fid & 63;
    int r0 = (lane >> 4) * 8, c = ct * 16 + (lane & 15);
    unsigned short o[8];
    #pragma unroll
    for (int j = 0; j < 8; ++j) o[j] = f2bf(ls[r0 + j][c]);
    reinterpret_cast<uint4*>(dst + (size_t)(ct * 64 + lane) * 8)[0] =
        make_uint4((unsigned)o[0] | ((unsigned)o[1] << 16),
                   (unsigned)o[2] | ((unsigned)o[3] << 16),
                   (unsigned)o[4] | ((unsigned)o[5] << 16),
                   (unsigned)o[6] | ((unsigned)o[7] << 16));
  }
}

// ---------------- router: no LDS, no atomics, 1 wave = 4 tokens ----------------
__global__ __launch_bounds__(256) void router_kernel(
    const float* __restrict__ x, const float* __restrict__ rw,
    Routing* __restrict__ routing) {
  const int lane = threadIdx.x & 63;
  const int wgid = blockIdx.x * 4 + (threadIdx.x >> 6);
  const int tok0 = wgid * 4;
  float acc[4][8];
  #pragma unroll
  for (int t = 0; t < 4; ++t)
    #pragma unroll
    for (int e = 0; e < 8; ++e) acc[t][e] = 0.f;
  const float4* xr = reinterpret_cast<const float4*>(x);
  const float4* wr = reinterpret_cast<const float4*>(rw);
  #pragma unroll
  for (int c = 0; c < 8; ++c) {
    float4 wv[8];
    #pragma unroll
    for (int e = 0; e < 8; ++e) wv[e] = wr[e * 512 + c * 64 + lane];
    #pragma unroll
    for (int t = 0; t < 4; ++t) {
      float4 xv = xr[(size_t)(tok0 + t) * 512 + c * 64 + lane];
      #pragma unroll
      for (int e = 0; e < 8; ++e)
        acc[t][e] += xv.x * wv[e].x + xv.y * wv[e].y + xv.z * wv[e].z + xv.w * wv[e].w;
    }
  }
  // xor 1,2,4: each 8-lane group holds its partial sum for all 8 experts
  #pragma unroll
  for (int t = 0; t < 4; ++t)
    #pragma unroll
    for (int e = 0; e < 8; ++e) {
      acc[t][e] += __shfl_xor(acc[t][e], 1);
      acc[t][e] += __shfl_xor(acc[t][e], 2);
      acc[t][e] += __shfl_xor(acc[t][e], 4);
    }
  const int l3 = lane & 7;
  #pragma unroll
  for (int t = 0; t < 4; ++t) {
    // lane selects expert (lane&7)'s partial, then sums across the 8 groups
    float v0 = (l3 & 1) ? acc[t][1] : acc[t][0];
    float v1 = (l3 & 1) ? acc[t][3] : acc[t][2];
    float v2 = (l3 & 1) ? acc[t][5] : acc[t][4];
    float v3 = (l3 & 1) ? acc[t][7] : acc[t][6];
    float u0 = (l3 & 2) ? v1 : v0;
    float u1 = (l3 & 2) ? v3 : v2;
    float sel = (l3 & 4) ? u1 : u0;
    sel += __shfl_xor(sel, 8);
    sel += __shfl_xor(sel, 16);
    sel += __shfl_xor(sel, 32);
    // lane e (e<8) now holds logit L_e; broadcast all 8 to every lane
    float le[8];
    #pragma unroll
    for (int e = 0; e < 8; ++e) le[e] = __shfl(sel, e);
    if (lane == 0) {
      int tok = tok0 + t;
      int i0 = 0; float m0 = le[0];
      #pragma unroll
      for (int e = 1; e < 8; ++e) if (le[e] > m0) { m0 = le[e]; i0 = e; }
      int i1 = -1; float m1 = -3.4e38f;
      #pragma unroll
      for (int e = 0; e < 8; ++e) if (e != i0 && le[e] > m1) { m1 = le[e]; i1 = e; }
      float ed = __expf(m1 - m0);                 // <= 1
      Routing r; r.i0 = i0; r.i1 = i1;
      r.w0 = 1.f / (1.f + ed); r.w1 = ed / (1.f + ed);
      routing[tok] = r;
    }
  }
}

// ---------------- count: one block per (slot,expert), atomic-free ----------------
__global__ __launch_bounds__(256) void count_kernel(
    const Routing* __restrict__ routing, int* __restrict__ cnt) {
  const int s = blockIdx.x >> 3, e = blockIdx.x & 7;
  const int tid = threadIdx.x;
  int c = 0;
  for (int t = tid; t < NTOK; t += 256) {
    Routing r = routing[t];
    c += ((s == 0 ? r.i0 : r.i1) == e);
  }
  c += __shfl_xor(c, 32); c += __shfl_xor(c, 16); c += __shfl_xor(c, 8);
  c += __shfl_xor(c, 4);  c += __shfl_xor(c, 2);  c += __shfl_xor(c, 1);
  __shared__ int wsum[4];
  if ((tid & 63) == 0) wsum[tid >> 6] = c;
  __syncthreads();
  if (tid == 0) cnt[blockIdx.x] = wsum[0] + wsum[1] + wsum[2] + wsum[3];
}

// ---------------- build: prefix offsets + XCD-grouped work table ----------------
__global__ void build_kernel(const int* __restrict__ cnt, int* __restrict__ cur,
                             int4* __restrict__ table) {
  const int tid = threadIdx.x;
  for (int i = tid; i < 2 * ENTRIES; i += 256)
    table[i] = make_int4(0, 0, 0, 0);          // rcnt==0 sentinel -> early exit
  __syncthreads();
  if (tid < 16) {                               // cur[s*8+e] = per-slot prefix
    int s = tid >> 3, e = tid & 7;
    int base = 0;
    for (int k = 0; k < e; ++k) base += cnt[s * 8 + k];
    cur[tid] = base;
  }
  __syncthreads();
  if (tid < 16) {                               // one thread per (slot, xcd)
    int s = tid >> 3, xcd = tid & 7;
    int j = 0;
    int base = 0;
    for (int e = 0; e < 8; ++e) {
      int c = cnt[s * 8 + e];
      #pragma unroll
      for (int nn = 0; nn < 2; ++nn) {
        int n = xcd + nn * 8;                   // heads with n%8 == xcd
        for (int t = 0; t < c; t += TILE) {
          int rc = c - t; if (rc > TILE) rc = TILE;
          table[s * ENTRIES + xcd + 8 * j] = make_int4(e, base + t, rc, n);
          ++j;
        }
      }
      base += c;
    }
  }
}

// ---------------- compact: ordered, atomic-free scatter via block scan ----------------
__global__ __launch_bounds__(256) void compact_kernel(
    const Routing* __restrict__ routing, const int* __restrict__ cur,
    int* __restrict__ list, float* __restrict__ wl) {
  const int s = blockIdx.x >> 3, e = blockIdx.x & 7;
  const int tid = threadIdx.x;
  __shared__ int ps[256];
  int myc = 0;
  for (int t = tid; t < NTOK; t += 256) {
    Routing r = routing[t];
    myc += ((s == 0 ? r.i0 : r.i1) == e);
  }
  ps[tid] = myc;
  __syncthreads();
  for (int off = 1; off < 256; off <<= 1) {     // inclusive log-step scan
    int v = (tid >= off) ? ps[tid - off] : 0;
    __syncthreads();
    ps[tid] += v;
    __syncthreads();
  }
  int base = cur[blockIdx.x] + ps[tid] - myc;   // exclusive prefix + slot base
  for (int t = tid; t < NTOK; t += 256) {
    Routing r = routing[t];
    int ei = (s == 0 ? r.i0 : r.i1);
    if (ei == e) {
      list[s * NTOK + base] = t;
      wl[s * NTOK + base] = (s == 0 ? r.w0 : r.w1);
      ++base;
    }
  }
}

// ---------------- fused expert: (x@W1)*silu(x@Wg) @ W2, scaled ----------------
// block: 32-token tile x 1 head, 4 waves, 32KB dynamic LDS (xs 8KB + G 24KB)
// -> 5 blocks/CU by LDS (vs 2 at 64KB): latency-hiding occupancy is the point.
__global__ __launch_bounds__(256, 5) void expert_kernel(
    const float* __restrict__ x,
    const unsigned short* __restrict__ w1P,
    const unsigned short* __restrict__ wgP,
    const unsigned short* __restrict__ w2P,
    const int* __restrict__ list, const float* __restrict__ wl,
    const int4* __restrict__ table,
    float* __restrict__ out, const int slot)
{
  extern __shared__ char smem[];
  char* xs = smem;            // 32 rows * 256B bf16, XOR-swizzled by (row&7)<<4
  char* G  = smem + 8192;     // 32 rows * 768B bf16, XOR-swizzled
  const int4 tb = table[slot * ENTRIES + blockIdx.x];
  const int e = tb.x, rbeg = tb.y, rcnt = tb.z, n = tb.w;
  if (rcnt == 0) return;
  const int* lst = list + slot * NTOK + rbeg;
  const float* wls = wl + slot * NTOK + rbeg;
  const int tid = threadIdx.x;

  // ---- gather x rows: fp32 global -> bf16 swizzled LDS ----
  {
    const int cpos = tid & 31;      // float4 index within a 128-float row
    const int rsub = tid >> 5;      // 0..7
    #pragma unroll
    for (int it = 0; it < 4; ++it) {
      int row = it * 8 + rsub;
      unsigned int lo = 0, hi = 0;
      if (row < rcnt) {
        int tok = lst[row];
        float4 v = reinterpret_cast<const float4*>(x + ((size_t)tok * NHEAD + n) * DDIM)[cpos];
        lo = (unsigned)f2bf(v.x) | ((unsigned)f2bf(v.y) << 16);
        hi = (unsigned)f2bf(v.z) | ((unsigned)f2bf(v.w) << 16);
      }
      int byte = row * 256 + ((cpos * 8) ^ ((row & 7) << 4));
      *reinterpret_cast<uint2*>(xs + byte) = make_uint2(lo, hi);
    }
  }
  __syncthreads();

  const int wid = tid >> 6, lane = tid & 63;
  const int lr = lane & 15, lq = lane >> 4;
  const f32x4 z4 = {0.f, 0.f, 0.f, 0.f};

  // ---- stage 1: G = (x@W1) * silu(x@Wg) ----
  short8 a[2][4];   // A-frags: 2 row-tiles x 4 k-steps, held in regs
  #pragma unroll
  for (int mi = 0; mi < 2; ++mi)
    #pragma unroll
    for (int kk = 0; kk < 4; ++kk) {
      int row = mi * 16 + lr;
      int byte = row * 256 + (((kk * 32 + lq * 8) * 2) ^ ((row & 7) << 4));
      a[mi][kk] = *reinterpret_cast<const short8*>(xs + byte);
    }
  const unsigned short* w1b = w1P + (size_t)(e * NHEAD + n) * (4 * 24 * 512);
  const unsigned short* wgb = wgP + (size_t)(e * NHEAD + n) * (4 * 24 * 512);
  for (int ct = 0; ct < 6; ++ct) {
    const int ctg = wid * 6 + ct;   // col-tile 0..23 (H=384)
    f32x4 ah[2], ag[2];
    #pragma unroll
    for (int mi = 0; mi < 2; ++mi) { ah[mi] = z4; ag[mi] = z4; }
    #pragma unroll
    for (int kk = 0; kk < 4; ++kk) {
      short8 b1 = *reinterpret_cast<const short8*>(w1b + ((size_t)(kk * 24 + ctg) * 64 + lane) * 8);
      short8 bg = *reinterpret_cast<const short8*>(wgb + ((size_t)(kk * 24 + ctg) * 64 + lane) * 8);
      #pragma unroll
      for (int mi = 0; mi < 2; ++mi) {
        ah[mi] = __builtin_amdgcn_mfma_f32_16x16x32_bf16(a[mi][kk], b1, ah[mi], 0, 0, 0);
        ag[mi] = __builtin_amdgcn_mfma_f32_16x16x32_bf16(a[mi][kk], bg, ag[mi], 0, 0, 0);
      }
    }
    #pragma unroll
    for (int mi = 0; mi < 2; ++mi)
      #pragma unroll
      for (int r = 0; r < 4; ++r) {
        float h1 = ah[mi][r], g = ag[mi][r];
        // silu via v_rcp_f32 (rel err ~2^-22 << bf16 rounding): saves the fp32 fdiv chain
        float val = h1 * g * __builtin_amdgcn_rcpf(1.f + __expf(-g));
        int row = mi * 16 + lq * 4 + r;              // C-layout: row=(l>>4)*4+r
        int col = ctg * 16 + lr;                     //           col=l&15
        int byte = row * 768 + ((col * 2) ^ ((row & 7) << 4));
        *reinterpret_cast<unsigned short*>(G + byte) = f2bf(val);
      }
  }
  __syncthreads();

  // ---- stage 2: out_tile = G @ W2, scale by routing weight ----
  const int rg = wid >> 1, cg = wid & 1;  // 2x2 wave grid over (row-tiles, col-halves)
  f32x4 acc[4];
  #pragma unroll
  for (int ct = 0; ct < 4; ++ct) acc[ct] = z4;
  const unsigned short* w2b = w2P + (size_t)(e * NHEAD + n) * (12 * 8 * 512);
  for (int kk = 0; kk < 12; ++kk) {
    int row0 = rg * 16 + lr;
    int byte0 = row0 * 768 + (((kk * 32 + lq * 8) * 2) ^ ((row0 & 7) << 4));
    short8 a0 = *reinterpret_cast<const short8*>(G + byte0);
    #pragma unroll
    for (int ct = 0; ct < 4; ++ct) {
      short8 b = *reinterpret_cast<const short8*>(w2b + ((size_t)(kk * 8 + cg * 4 + ct) * 64 + lane) * 8);
      acc[ct] = __builtin_amdgcn_mfma_f32_16x16x32_bf16(a0, b, acc[ct], 0, 0, 0);
    }
  }
  #pragma unroll
  for (int r = 0; r < 4; ++r) {
    int row = rg * 16 + lq * 4 + r;
    if (row < rcnt) {
      int tok = lst[row];
      float wt = wls[row];
      float* op = out + ((size_t)tok * NHEAD + n) * DDIM;
      #pragma unroll
      for (int ct = 0; ct < 4; ++ct) {
        int col = (cg * 4 + ct) * 16 + lr;
        float v = acc[ct][r] * wt;
        if (slot == 0) op[col] = v;   // pass 0: every token exactly once -> full coverage
        else          op[col] += v;   // pass 1: unique writer, stream-ordered after pass 0
      }
    }
  }
}

extern "C" void kernel_launch(void* const* d_in, const int* in_sizes, int n_in,
                              void* d_out, int out_size, void* d_ws, size_t ws_size,
                              hipStream_t stream) {
  const float* x  = (const float*)d_in[0];
  const float* rw = (const float*)d_in[1];
  const float* w1 = (const float*)d_in[2];
  const float* wg = (const float*)d_in[3];
  const float* w2 = (const float*)d_in[4];
  float* out = (float*)d_out;
  char* ws = (char*)d_ws;

  unsigned short* w1P = (unsigned short*)(ws + OFF_W1P);
  unsigned short* wgP = (unsigned short*)(ws + OFF_WGP);
  unsigned short* w2P = (unsigned short*)(ws + OFF_W2P);
  Routing* routing = (Routing*)(ws + OFF_ROUT);
  int* cnt = (int*)(ws + OFF_CNT);
  int* cur = cnt + 16;
  int4* table = (int4*)(ws + OFF_TAB);
  int* list = (int*)(ws + OFF_LIST);
  float* wl = (float*)(ws + OFF_WL);

  convA_kernel<<<dim3(4, 128, 2), 256, 0, stream>>>(w1, wg, w1P, wgP);
  convB_kernel<<<dim3(12, 128, 1), 256, 0, stream>>>(w2, w2P);
  router_kernel<<<512, 256, 0, stream>>>(x, rw, routing);
  count_kernel<<<16, 256, 0, stream>>>(routing, cnt);
  build_kernel<<<1, 256, 0, stream>>>(cnt, cur, table);
  compact_kernel<<<16, 256, 0, stream>>>(routing, cur, list, wl);
  expert_kernel<<<ENTRIES, 256, 32768, stream>>>(
      x, w1P, wgP, w2P, list, wl, table, out, 0);
  expert_kernel<<<ENTRIES, 256, 32768, stream>>>(
      x, w1P, wgP, w2P, list, wl, table, out, 1);
}

// Round 5
// 299.831 us; speedup vs baseline: 1.9716x; 1.1271x over previous
//
#include <hip/hip_runtime.h>

#define NTOK  8192
#define NHEAD 16
#define DDIM  128
#define HDIM  384
#define NEXP  8
#define TILE  64
#define ENTRIES 2176   // per-slot work entries; worst case lid = 7 + 8*269 = 2159

typedef __attribute__((ext_vector_type(8))) short short8;   // 8 x bf16 (4 VGPRs)
typedef __attribute__((ext_vector_type(4))) float f32x4;    // MFMA accumulator

// ---------------- workspace layout (bytes) ----------------
#define SZ_W1P   (8UL*16*4*24*512*2)          // 12,582,912
#define OFF_W1P  0UL
#define OFF_WGP  (OFF_W1P + SZ_W1P)
#define OFF_W2P  (OFF_WGP + SZ_W1P)
#define SZ_W2P   (8UL*16*12*8*512*2)          // 12,582,912
#define OFF_ROUT (OFF_W2P + SZ_W2P)           // Routing[8192], 16B each
#define OFF_CNT  (OFF_ROUT + 8192UL*16)       // cnt[16], cur[16]
#define OFF_TAB  (OFF_CNT + 256)              // int4[2][ENTRIES]
#define OFF_LIST (OFF_TAB + 2UL*ENTRIES*16)   // int[2][8192]
#define OFF_WL   (OFF_LIST + 2UL*8192*4)      // float[2][8192]

struct Routing { int i0, i1; float w0, w1; };

__device__ __forceinline__ unsigned short f2bf(float f) {
  unsigned int u = __float_as_uint(f);
  u += 0x7fffu + ((u >> 16) & 1u);            // round-to-nearest-even
  return (unsigned short)(u >> 16);
}

// ---------------- weight conversion: fp32 -> bf16 fragment-packed ----------------
// w1/w_gate: [e][n][d=128][h=384] -> frag [en][kk(4)][ct(24)][lane(64)][8]
// element (kk,ct,lane,j) = src[d = kk*32 + (lane>>4)*8 + j][h = ct*16 + (lane&15)]
__global__ __launch_bounds__(256) void convA_kernel(
    const float* __restrict__ w1, const float* __restrict__ wg,
    unsigned short* __restrict__ w1P, unsigned short* __restrict__ wgP) {
  __shared__ float ls[32][388];
  const int kk = blockIdx.x;          // 0..3
  const int en = blockIdx.y;          // 0..127
  const float* src = (blockIdx.z == 0 ? w1 : wg) + ((size_t)en * DDIM + kk * 32) * HDIM;
  unsigned short* dst = (blockIdx.z == 0 ? w1P : wgP) + ((size_t)en * 4 + kk) * (24 * 512);
  const int tid = threadIdx.x;
  #pragma unroll
  for (int i = 0; i < 12; ++i) {
    int f4 = i * 256 + tid;           // 3072 float4 = 32x384
    int row = f4 / 96, c4 = f4 % 96;
    float4 v = reinterpret_cast<const float4*>(src + (size_t)row * HDIM)[c4];
    ls[row][c4*4+0] = v.x; ls[row][c4*4+1] = v.y;
    ls[row][c4*4+2] = v.z; ls[row][c4*4+3] = v.w;
  }
  __syncthreads();
  #pragma unroll
  for (int i = 0; i < 6; ++i) {
    int fid = i * 256 + tid;          // 1536 = 24ct * 64lane
    int ct = fid >> 6, lane = fid & 63;
    int r0 = (lane >> 4) * 8, c = ct * 16 + (lane & 15);
    unsigned short o[8];
    #pragma unroll
    for (int j = 0; j < 8; ++j) o[j] = f2bf(ls[r0 + j][c]);
    reinterpret_cast<uint4*>(dst + (size_t)(ct * 64 + lane) * 8)[0] =
        make_uint4((unsigned)o[0] | ((unsigned)o[1] << 16),
                   (unsigned)o[2] | ((unsigned)o[3] << 16),
                   (unsigned)o[4] | ((unsigned)o[5] << 16),
                   (unsigned)o[6] | ((unsigned)o[7] << 16));
  }
}

// w2: [e][n][h=384][d=128] -> frag [en][kk(12)][ct(8)][lane(64)][8]
// element = src[h = kk*32 + (lane>>4)*8 + j][d = ct*16 + (lane&15)]
__global__ __launch_bounds__(256) void convB_kernel(
    const float* __restrict__ w2, unsigned short* __restrict__ w2P) {
  __shared__ float ls[32][132];
  const int kk = blockIdx.x;          // 0..11
  const int en = blockIdx.y;
  const float* src = w2 + ((size_t)en * HDIM + kk * 32) * DDIM;
  unsigned short* dst = w2P + ((size_t)en * 12 + kk) * (8 * 512);
  const int tid = threadIdx.x;
  #pragma unroll
  for (int i = 0; i < 4; ++i) {
    int f4 = i * 256 + tid;           // 1024 float4 = 32x128
    int row = f4 >> 5, c4 = f4 & 31;
    float4 v = reinterpret_cast<const float4*>(src + (size_t)row * DDIM)[c4];
    ls[row][c4*4+0] = v.x; ls[row][c4*4+1] = v.y;
    ls[row][c4*4+2] = v.z; ls[row][c4*4+3] = v.w;
  }
  __syncthreads();
  #pragma unroll
  for (int i = 0; i < 2; ++i) {
    int fid = i * 256 + tid;          // 512 = 8ct * 64lane
    int ct = fid >> 6, lane = fid & 63;
    int r0 = (lane >> 4) * 8, c = ct * 16 + (lane & 15);
    unsigned short o[8];
    #pragma unroll
    for (int j = 0; j < 8; ++j) o[j] = f2bf(ls[r0 + j][c]);
    reinterpret_cast<uint4*>(dst + (size_t)(ct * 64 + lane) * 8)[0] =
        make_uint4((unsigned)o[0] | ((unsigned)o[1] << 16),
                   (unsigned)o[2] | ((unsigned)o[3] << 16),
                   (unsigned)o[4] | ((unsigned)o[5] << 16),
                   (unsigned)o[6] | ((unsigned)o[7] << 16));
  }
}

// ---------------- router: no LDS, no atomics, 1 wave = 4 tokens ----------------
__global__ __launch_bounds__(256) void router_kernel(
    const float* __restrict__ x, const float* __restrict__ rw,
    Routing* __restrict__ routing) {
  const int lane = threadIdx.x & 63;
  const int wgid = blockIdx.x * 4 + (threadIdx.x >> 6);
  const int tok0 = wgid * 4;
  float acc[4][8];
  #pragma unroll
  for (int t = 0; t < 4; ++t)
    #pragma unroll
    for (int e = 0; e < 8; ++e) acc[t][e] = 0.f;
  const float4* xr = reinterpret_cast<const float4*>(x);
  const float4* wr = reinterpret_cast<const float4*>(rw);
  #pragma unroll
  for (int c = 0; c < 8; ++c) {
    float4 wv[8];
    #pragma unroll
    for (int e = 0; e < 8; ++e) wv[e] = wr[e * 512 + c * 64 + lane];
    #pragma unroll
    for (int t = 0; t < 4; ++t) {
      float4 xv = xr[(size_t)(tok0 + t) * 512 + c * 64 + lane];
      #pragma unroll
      for (int e = 0; e < 8; ++e)
        acc[t][e] += xv.x * wv[e].x + xv.y * wv[e].y + xv.z * wv[e].z + xv.w * wv[e].w;
    }
  }
  // xor 1,2,4: each 8-lane group holds its partial sum for all 8 experts
  #pragma unroll
  for (int t = 0; t < 4; ++t)
    #pragma unroll
    for (int e = 0; e < 8; ++e) {
      acc[t][e] += __shfl_xor(acc[t][e], 1);
      acc[t][e] += __shfl_xor(acc[t][e], 2);
      acc[t][e] += __shfl_xor(acc[t][e], 4);
    }
  const int l3 = lane & 7;
  #pragma unroll
  for (int t = 0; t < 4; ++t) {
    // lane selects expert (lane&7)'s partial, then sums across the 8 groups
    float v0 = (l3 & 1) ? acc[t][1] : acc[t][0];
    float v1 = (l3 & 1) ? acc[t][3] : acc[t][2];
    float v2 = (l3 & 1) ? acc[t][5] : acc[t][4];
    float v3 = (l3 & 1) ? acc[t][7] : acc[t][6];
    float u0 = (l3 & 2) ? v1 : v0;
    float u1 = (l3 & 2) ? v3 : v2;
    float sel = (l3 & 4) ? u1 : u0;
    sel += __shfl_xor(sel, 8);
    sel += __shfl_xor(sel, 16);
    sel += __shfl_xor(sel, 32);
    // lane e (e<8) now holds logit L_e; broadcast all 8 to every lane
    float le[8];
    #pragma unroll
    for (int e = 0; e < 8; ++e) le[e] = __shfl(sel, e);
    if (lane == 0) {
      int tok = tok0 + t;
      int i0 = 0; float m0 = le[0];
      #pragma unroll
      for (int e = 1; e < 8; ++e) if (le[e] > m0) { m0 = le[e]; i0 = e; }
      int i1 = -1; float m1 = -3.4e38f;
      #pragma unroll
      for (int e = 0; e < 8; ++e) if (e != i0 && le[e] > m1) { m1 = le[e]; i1 = e; }
      float ed = __expf(m1 - m0);                 // <= 1
      Routing r; r.i0 = i0; r.i1 = i1;
      r.w0 = 1.f / (1.f + ed); r.w1 = ed / (1.f + ed);
      routing[tok] = r;
    }
  }
}

// ---------------- count: one block per (slot,expert), atomic-free ----------------
__global__ __launch_bounds__(256) void count_kernel(
    const Routing* __restrict__ routing, int* __restrict__ cnt) {
  const int s = blockIdx.x >> 3, e = blockIdx.x & 7;
  const int tid = threadIdx.x;
  int c = 0;
  for (int t = tid; t < NTOK; t += 256) {
    Routing r = routing[t];
    c += ((s == 0 ? r.i0 : r.i1) == e);
  }
  c += __shfl_xor(c, 32); c += __shfl_xor(c, 16); c += __shfl_xor(c, 8);
  c += __shfl_xor(c, 4);  c += __shfl_xor(c, 2);  c += __shfl_xor(c, 1);
  __shared__ int wsum[4];
  if ((tid & 63) == 0) wsum[tid >> 6] = c;
  __syncthreads();
  if (tid == 0) cnt[blockIdx.x] = wsum[0] + wsum[1] + wsum[2] + wsum[3];
}

// ---------------- build: prefix offsets + XCD-grouped work table ----------------
__global__ void build_kernel(const int* __restrict__ cnt, int* __restrict__ cur,
                             int4* __restrict__ table) {
  const int tid = threadIdx.x;
  for (int i = tid; i < 2 * ENTRIES; i += 256)
    table[i] = make_int4(0, 0, 0, 0);          // rcnt==0 sentinel -> early exit
  __syncthreads();
  if (tid < 16) {                               // cur[s*8+e] = per-slot prefix
    int s = tid >> 3, e = tid & 7;
    int base = 0;
    for (int k = 0; k < e; ++k) base += cnt[s * 8 + k];
    cur[tid] = base;
  }
  __syncthreads();
  if (tid < 16) {                               // one thread per (slot, xcd)
    int s = tid >> 3, xcd = tid & 7;
    int j = 0;
    int base = 0;
    for (int e = 0; e < 8; ++e) {
      int c = cnt[s * 8 + e];
      #pragma unroll
      for (int nn = 0; nn < 2; ++nn) {
        int n = xcd + nn * 8;                   // heads with n%8 == xcd
        for (int t = 0; t < c; t += TILE) {
          int rc = c - t; if (rc > TILE) rc = TILE;
          table[s * ENTRIES + xcd + 8 * j] = make_int4(e, base + t, rc, n);
          ++j;
        }
      }
      base += c;
    }
  }
}

// ---------------- compact: ordered, atomic-free scatter via block scan ----------------
__global__ __launch_bounds__(256) void compact_kernel(
    const Routing* __restrict__ routing, const int* __restrict__ cur,
    int* __restrict__ list, float* __restrict__ wl) {
  const int s = blockIdx.x >> 3, e = blockIdx.x & 7;
  const int tid = threadIdx.x;
  __shared__ int ps[256];
  int myc = 0;
  for (int t = tid; t < NTOK; t += 256) {
    Routing r = routing[t];
    myc += ((s == 0 ? r.i0 : r.i1) == e);
  }
  ps[tid] = myc;
  __syncthreads();
  for (int off = 1; off < 256; off <<= 1) {     // inclusive log-step scan
    int v = (tid >= off) ? ps[tid - off] : 0;
    __syncthreads();
    ps[tid] += v;
    __syncthreads();
  }
  int base = cur[blockIdx.x] + ps[tid] - myc;   // exclusive prefix + slot base
  for (int t = tid; t < NTOK; t += 256) {
    Routing r = routing[t];
    int ei = (s == 0 ? r.i0 : r.i1);
    if (ei == e) {
      list[s * NTOK + base] = t;
      wl[s * NTOK + base] = (s == 0 ? r.w0 : r.w1);
      ++base;
    }
  }
}

// ---------------- fused expert: (x@W1)*silu(x@Wg) @ W2, scaled ----------------
// 64 tokens x 1 head per block; 4 waves each own 16 tokens with out[16][128]
// in registers. All waves load IDENTICAL weight fragments (L1 broadcast).
// Barrier-free main loop: per 32-h chunk, stage1 MFMAs -> silu -> wave-private
// LDS transpose (lgkmcnt-ordered, no __syncthreads) -> stage2 MFMAs into acc.
__global__ __launch_bounds__(256, 4) void expert_kernel(
    const float* __restrict__ x,
    const unsigned short* __restrict__ w1P,
    const unsigned short* __restrict__ wgP,
    const unsigned short* __restrict__ w2P,
    const int* __restrict__ list, const float* __restrict__ wl,
    const int4* __restrict__ table,
    float* __restrict__ out, const int slot)
{
  extern __shared__ char smem[];
  char* xs = smem;            // 64 rows * 256B bf16, XOR-swizzled by (row&7)<<4
  char* Pb = smem + 16384;    // 4 waves * 1536B: P scratch, 16 rows * 80B (pad)
  const int4 tb = table[slot * ENTRIES + blockIdx.x];
  const int e = tb.x, rbeg = tb.y, rcnt = tb.z, n = tb.w;
  if (rcnt == 0) return;
  const int* lst = list + slot * NTOK + rbeg;
  const float* wls = wl + slot * NTOK + rbeg;
  const int tid = threadIdx.x;

  // ---- gather x rows: fp32 global -> bf16 swizzled LDS ----
  {
    const int cpos = tid & 31;      // float4 index within a 128-float row
    const int rsub = tid >> 5;      // 0..7
    #pragma unroll
    for (int it = 0; it < 8; ++it) {
      int row = it * 8 + rsub;
      unsigned int lo = 0, hi = 0;
      if (row < rcnt) {
        int tok = lst[row];
        float4 v = reinterpret_cast<const float4*>(x + ((size_t)tok * NHEAD + n) * DDIM)[cpos];
        lo = (unsigned)f2bf(v.x) | ((unsigned)f2bf(v.y) << 16);
        hi = (unsigned)f2bf(v.z) | ((unsigned)f2bf(v.w) << 16);
      }
      int byte = row * 256 + ((cpos * 8) ^ ((row & 7) << 4));
      *reinterpret_cast<uint2*>(xs + byte) = make_uint2(lo, hi);
    }
  }
  __syncthreads();               // the ONLY block-wide barrier

  const int wid = tid >> 6, lane = tid & 63;
  const int lr = lane & 15, lq = lane >> 4;
  char* pw = Pb + wid * 1536;    // wave-private transpose scratch
  const f32x4 z4 = {0.f, 0.f, 0.f, 0.f};

  // x A-frags for this wave's 16 tokens (rows wid*16 .. wid*16+15)
  short8 a[4];
  #pragma unroll
  for (int kk = 0; kk < 4; ++kk) {
    int row = wid * 16 + lr;
    int byte = row * 256 + (((kk * 32 + lq * 8) * 2) ^ ((row & 7) << 4));
    a[kk] = *reinterpret_cast<const short8*>(xs + byte);
  }

  f32x4 acc[8];                  // out[16 tok][128 d] = 8 col-tiles
  #pragma unroll
  for (int ct = 0; ct < 8; ++ct) acc[ct] = z4;

  const unsigned short* w1b = w1P + (size_t)(e * NHEAD + n) * (4 * 24 * 512);
  const unsigned short* wgb = wgP + (size_t)(e * NHEAD + n) * (4 * 24 * 512);
  const unsigned short* w2b = w2P + (size_t)(e * NHEAD + n) * (12 * 8 * 512);

  for (int c = 0; c < 12; ++c) {       // 12 chunks of 32 h-values
    // ---- stage 1: P[16 tok][32 h] = (x@W1) * silu(x@Wg), chunk slice ----
    #pragma unroll
    for (int ct2 = 0; ct2 < 2; ++ct2) {
      const int ctg = c * 2 + ct2;     // col-tile 0..23
      f32x4 ah = z4, ag = z4;
      #pragma unroll
      for (int kk = 0; kk < 4; ++kk) {
        short8 b1 = *reinterpret_cast<const short8*>(w1b + ((size_t)(kk * 24 + ctg) * 64 + lane) * 8);
        short8 bg = *reinterpret_cast<const short8*>(wgb + ((size_t)(kk * 24 + ctg) * 64 + lane) * 8);
        ah = __builtin_amdgcn_mfma_f32_16x16x32_bf16(a[kk], b1, ah, 0, 0, 0);
        ag = __builtin_amdgcn_mfma_f32_16x16x32_bf16(a[kk], bg, ag, 0, 0, 0);
      }
      #pragma unroll
      for (int r = 0; r < 4; ++r) {
        float h1 = ah[r], g = ag[r];
        float val = h1 * g * __builtin_amdgcn_rcpf(1.f + __expf(-g));  // silu
        int row = lq * 4 + r;          // C-layout: token row=(l>>4)*4+r
        int hl = ct2 * 16 + lr;        //           h col = l&15
        *reinterpret_cast<unsigned short*>(pw + row * 80 + hl * 2) = f2bf(val);
      }
    }
    // ---- stage 2: acc += P @ W2 chunk (K=32); wave-private read, no barrier ----
    short8 a2 = *reinterpret_cast<const short8*>(pw + lr * 80 + lq * 16);
    #pragma unroll
    for (int ct = 0; ct < 8; ++ct) {
      short8 b = *reinterpret_cast<const short8*>(w2b + ((size_t)(c * 8 + ct) * 64 + lane) * 8);
      acc[ct] = __builtin_amdgcn_mfma_f32_16x16x32_bf16(a2, b, acc[ct], 0, 0, 0);
    }
  }

  // ---- epilogue: scale by routing weight, store/accumulate ----
  #pragma unroll
  for (int r = 0; r < 4; ++r) {
    int lrow = wid * 16 + lq * 4 + r;
    if (lrow < rcnt) {
      int tok = lst[lrow];
      float wt = wls[lrow];
      float* op = out + ((size_t)tok * NHEAD + n) * DDIM;
      #pragma unroll
      for (int ct = 0; ct < 8; ++ct) {
        int col = ct * 16 + lr;
        float v = acc[ct][r] * wt;
        if (slot == 0) op[col] = v;   // pass 0: every token exactly once
        else          op[col] += v;   // pass 1: unique writer, after pass 0
      }
    }
  }
}

extern "C" void kernel_launch(void* const* d_in, const int* in_sizes, int n_in,
                              void* d_out, int out_size, void* d_ws, size_t ws_size,
                              hipStream_t stream) {
  const float* x  = (const float*)d_in[0];
  const float* rw = (const float*)d_in[1];
  const float* w1 = (const float*)d_in[2];
  const float* wg = (const float*)d_in[3];
  const float* w2 = (const float*)d_in[4];
  float* out = (float*)d_out;
  char* ws = (char*)d_ws;

  unsigned short* w1P = (unsigned short*)(ws + OFF_W1P);
  unsigned short* wgP = (unsigned short*)(ws + OFF_WGP);
  unsigned short* w2P = (unsigned short*)(ws + OFF_W2P);
  Routing* routing = (Routing*)(ws + OFF_ROUT);
  int* cnt = (int*)(ws + OFF_CNT);
  int* cur = cnt + 16;
  int4* table = (int4*)(ws + OFF_TAB);
  int* list = (int*)(ws + OFF_LIST);
  float* wl = (float*)(ws + OFF_WL);

  convA_kernel<<<dim3(4, 128, 2), 256, 0, stream>>>(w1, wg, w1P, wgP);
  convB_kernel<<<dim3(12, 128, 1), 256, 0, stream>>>(w2, w2P);
  router_kernel<<<512, 256, 0, stream>>>(x, rw, routing);
  count_kernel<<<16, 256, 0, stream>>>(routing, cnt);
  build_kernel<<<1, 256, 0, stream>>>(cnt, cur, table);
  compact_kernel<<<16, 256, 0, stream>>>(routing, cur, list, wl);
  expert_kernel<<<ENTRIES, 256, 22528, stream>>>(
      x, w1P, wgP, w2P, list, wl, table, out, 0);
  expert_kernel<<<ENTRIES, 256, 22528, stream>>>(
      x, w1P, wgP, w2P, list, wl, table, out, 1);
}